// Round 13
// baseline (185.212 us; speedup 1.0000x reference)
//
#include <hip/hip_runtime.h>

#define N_EDGES_C 1048576

typedef __attribute__((ext_vector_type(8))) __bf16 bf16x8;
typedef __attribute__((ext_vector_type(4))) __bf16 bf16x4;
typedef __attribute__((ext_vector_type(4))) float f32x4;
typedef __attribute__((ext_vector_type(4))) unsigned int u32x4;

#define MFMA16(a,b,c) __builtin_amdgcn_mfma_f32_16x16x32_bf16((a),(b),(c),0,0,0)

// LDS-visible barrier that does NOT drain vmcnt: staged weight-chunk loads stay in flight.
#define BARRIER() do { asm volatile("s_waitcnt lgkmcnt(0)" ::: "memory"); \
                       __builtin_amdgcn_s_barrier(); \
                       asm volatile("" ::: "memory"); } while (0)

__device__ __forceinline__ unsigned short f2bf(float f) {
  unsigned int u = __builtin_bit_cast(unsigned int, f);
  u = (u + 0x7fffu + ((u >> 16) & 1u)) >> 16;
  return (unsigned short)u;
}
__device__ __forceinline__ float bf2f(unsigned short h) {
  unsigned int u = ((unsigned int)h) << 16;
  return __builtin_bit_cast(float, u);
}

// swizzled 128x128 bf16 LDS tile (row stride 256B, byte ^= (row&7)<<4)
__device__ __forceinline__ bf16x8 fragM(const unsigned short* sM, int row, int kb, int lane) {
  int r = row + (lane & 15);
  int cb = (kb + ((lane >> 4) << 3)) * 2;
  return *(const bf16x8*)((const char*)sM + r * 256 + (cb ^ ((r & 7) << 4)));
}
__device__ __forceinline__ void putBf(unsigned short* sM, int r, int c, float v) {
  *(__bf16*)((char*)sM + r * 256 + ((c * 2) ^ ((r & 7) << 4))) = (__bf16)v;
}
// Adj counts: u8 [128][128], row stride 128B, byte col ^= (row&7)<<3 (register-only decode)
__device__ __forceinline__ bf16x8 adjFrag(const unsigned char* sCc, float inv,
                                          int mBase, int kb, int lane) {
  int m = mBase + (lane & 15);
  int c = (kb + ((lane >> 4) << 3)) ^ ((m & 7) << 3);
  const unsigned int* p = (const unsigned int*)(sCc + m * 128 + c);
  unsigned int w0 = p[0], w1 = p[1];
  bf16x8 r;
#pragma unroll
  for (int i = 0; i < 4; i++) {
    r[i]     = (__bf16)((float)((w0 >> (8 * i)) & 0xffu) * inv);
    r[4 + i] = (__bf16)((float)((w1 >> (8 * i)) & 0xffu) * inv);
  }
  return r;
}

// 16KB weight chunk: [128 rows][64 k] u16, row 128B = 8 x 16B slots; phys slot = (sl + row) & 7.
__device__ __forceinline__ void stG64(const unsigned short* src, int K, int ko, int t,
                                      u32x4& a, u32x4& b) {
  int row = t >> 2, s = t & 3;
  a = *(const u32x4*)(src + row * K + ko + s * 8);
  b = *(const u32x4*)(src + row * K + ko + (s + 4) * 8);
}
__device__ __forceinline__ void stW64(unsigned short* buf, int t, u32x4 a, u32x4 b) {
  int row = t >> 2, s = t & 3;
  *(u32x4*)((char*)buf + row * 128 + (((s + row) & 7) * 16)) = a;
  *(u32x4*)((char*)buf + row * 128 + (((s + 4 + row) & 7) * 16)) = b;
}
// read elements kb + gq*8 (kb in {0,32}): logical slot = kb/8 + gq
__device__ __forceinline__ bf16x8 fragW64(const unsigned short* buf, int nc, int kb, int lane) {
  int r = nc + (lane & 15);
  int sl = (kb >> 3) + (lane >> 4);
  return *(const bf16x8*)((const char*)buf + r * 128 + (((sl + r) & 7) * 16));
}

// ---------------- prep: bf16-transpose weights + fold BN + transpose readout W ----------------
__global__ void prep_kernel(const float* __restrict__ Wc0s, const float* __restrict__ Wc0n,
                            const float* __restrict__ Wc1s, const float* __restrict__ Wc1n,
                            const float* __restrict__ Wa,
                            const float* __restrict__ bc0, const float* __restrict__ g0,
                            const float* __restrict__ b0, const float* __restrict__ m0,
                            const float* __restrict__ v0,
                            const float* __restrict__ bc1, const float* __restrict__ g1,
                            const float* __restrict__ b1, const float* __restrict__ m1,
                            const float* __restrict__ v1,
                            const float* __restrict__ Wr0, const float* __restrict__ Wr1,
                            unsigned short* __restrict__ wbf, float* __restrict__ cst,
                            float* __restrict__ wr0t, float* __restrict__ wr1t) {
  int t = blockIdx.x * blockDim.x + threadIdx.x;
  if (t < 8192) {                       // 64x128 -> [d][f]
    int d = t >> 6, f = t & 63;
    wbf[t]        = f2bf(Wc0s[f * 128 + d]);
    wbf[8192 + t] = f2bf(Wc0n[f * 128 + d]);
  } else if (t < 24576) {               // 128x128 -> [d][k]
    int i = t - 8192;
    int d = i >> 7, k = i & 127;
    wbf[16384 + i] = f2bf(Wc1s[k * 128 + d]);
    wbf[32768 + i] = f2bf(Wc1n[k * 128 + d]);
    wbf[49152 + i] = f2bf(Wa[k * 128 + d]);
  } else if (t < 24704) {
    int d = t - 24576;
    float s0 = g0[d] * rsqrtf(v0[d] + 1e-5f);
    cst[d]       = s0;
    cst[128 + d] = (bc0[d] - m0[d]) * s0 + b0[d];
    float s1 = g1[d] * rsqrtf(v1[d] + 1e-5f);
    cst[256 + d] = s1;
    cst[384 + d] = (bc1[d] - m1[d]) * s1 + b1[d];
  } else if (t < 57472) {               // readout weights f32 transpose
    int i = t - 24704;
    int which = i >> 14;
    int k = i & 16383;
    int d = k >> 7, j = k & 127;
    float v = (which ? Wr1 : Wr0)[j * 128 + d];
    (which ? wr1t : wr0t)[k] = v;
  }
}

// ---------------- fused per-graph kernel: 1 block = 1 graph, exactly 80KB LDS, 2 blocks/CU ----------------
__global__ __launch_bounds__(512, 4)
void gnn_fused(const float* __restrict__ x, const float* __restrict__ mwt,
               const int* __restrict__ ei,
               const unsigned short* __restrict__ wbf, const float* __restrict__ cst,
               const float* __restrict__ ba,
               float* __restrict__ pooled) {
  __shared__ unsigned short sM[128 * 128];   // 32KB: x / V^T / h / p (swizzled)
  __shared__ unsigned char  sC[128 * 128];   // 16KB: Adj u8 counts -> (Ph8+) sPool/sV1 f32
  __shared__ unsigned short sWA[8192];       // 16KB weight chunk A
  __shared__ unsigned short sWB[8192];       // 16KB weight chunk B
  float* S3f = (float*)sC;                   // [0:128]=pool, [128:256]=row/col sums

  const int gb = blockIdx.x;
  const int t = threadIdx.x;
  const int lane = t & 63;
  const int w = t >> 6;              // wave 0..7
  const int col = lane & 15;
  const int gq = lane >> 4;
  const int r0 = gq << 2;
  const f32x4 zero = {0.f, 0.f, 0.f, 0.f};
  u32x4 sa, sb;                      // in-flight stage regs

  // ---- Ph0: issue W0n (full K=64 chunk); edge loads; zero counts; x -> sM
  stG64(wbf + 8192, 64, 0, t, sa, sb);
  int els, eld;
  {
    int e = gb * 512 + t;
    els = ei[e] & 127;
    eld = ei[N_EDGES_C + e] & 127;
  }
  {
    unsigned int* c32 = (unsigned int*)sC;
    for (int i = t; i < 4096; i += 512) c32[i] = 0u;
  }
  {
    const float4* xg = (const float4*)(x + (size_t)gb * 8192);
#pragma unroll
    for (int i = 0; i < 4; i++) {
      int vi = t + i * 512;
      float4 v = xg[vi];
      int node = vi >> 4;
      int f = (vi & 15) * 4;
      bf16x4 q = {(__bf16)v.x, (__bf16)v.y, (__bf16)v.z, (__bf16)v.w};
      *(bf16x4*)((char*)sM + node * 256 + ((f * 2) ^ ((node & 7) << 4))) = q;
    }
  }
  BARRIER();

  // ---- Ph1: histogram; commit W0n->A; xA preload
  {
    int cb = els ^ ((eld & 7) << 3);
    int idx = eld * 128 + cb;
    atomicAdd((unsigned int*)(sC + (idx & ~3)), 1u << ((idx & 3) * 8));
  }
  stW64(sWA, t, sa, sb);
  bf16x8 xA0 = fragM(sM, w * 16, 0, lane);
  bf16x8 xA1 = fragM(sM, w * 16, 32, lane);
  BARRIER();

  f32x4 acc[8];

  // ---- Ph2: issue W0s; V0 = xA@A; epiV V0^T -> sM (x dead: held in xA regs)
  stG64(wbf, 64, 0, t, sa, sb);
#pragma unroll
  for (int n = 0; n < 8; n++) acc[n] = zero;
#pragma unroll
  for (int n = 0; n < 8; n++) acc[n] = MFMA16(xA0, fragW64(sWA, n * 16, 0, lane), acc[n]);
#pragma unroll
  for (int n = 0; n < 8; n++) acc[n] = MFMA16(xA1, fragW64(sWA, n * 16, 32, lane), acc[n]);
#pragma unroll
  for (int n = 0; n < 8; n++) {  // V0^T[d][node]
    bf16x4 q = {(__bf16)acc[n][0], (__bf16)acc[n][1], (__bf16)acc[n][2], (__bf16)acc[n][3]};
    int d = n * 16 + col;
    *(bf16x4*)((char*)sM + d * 256 + (((w * 16 + r0) * 2) ^ ((d & 7) << 4))) = q;
  }
  BARRIER();

  // ---- Ph3: commit W0s->B; issue W1n-klo; inv_deg in-register; acc = Adj@V0
  stW64(sWB, t, sa, sb);
  stG64(wbf + 32768, 128, 0, t, sa, sb);
  float invRow;
  {
    int m = w * 16 + col;
    int sw = (m & 7) << 3;
    int ssum = 0;
#pragma unroll
    for (int i = 0; i < 8; i++) {
      unsigned int v = *(const unsigned int*)(sC + m * 128 + ((gq * 32 + i * 4) ^ sw));
      ssum += (int)(v & 0xff) + (int)((v >> 8) & 0xff) + (int)((v >> 16) & 0xff) + (int)(v >> 24);
    }
    ssum += __shfl_xor(ssum, 16);
    ssum += __shfl_xor(ssum, 32);
    invRow = 1.f / (float)(ssum > 1 ? ssum : 1);
  }
#pragma unroll
  for (int n = 0; n < 8; n++) acc[n] = zero;
  for (int kb = 0; kb < 4; kb++) {
    bf16x8 aF = adjFrag(sC, invRow, w * 16, kb * 32, lane);
#pragma unroll
    for (int n = 0; n < 8; n++)
      acc[n] = MFMA16(aF, fragM(sM, n * 16, kb * 32, lane), acc[n]);
  }
  BARRIER();

  // ---- Ph4: commit W1n-klo->A; acc += xA@B (W0s); BN0 epi -> h1; hA preload; issue W1n-khi
  stW64(sWA, t, sa, sb);
  stG64(wbf + 32768, 128, 64, t, sa, sb);
#pragma unroll
  for (int n = 0; n < 8; n++) acc[n] = MFMA16(xA0, fragW64(sWB, n * 16, 0, lane), acc[n]);
#pragma unroll
  for (int n = 0; n < 8; n++) acc[n] = MFMA16(xA1, fragW64(sWB, n * 16, 32, lane), acc[n]);
#pragma unroll
  for (int n = 0; n < 8; n++) {
    int d = n * 16 + col;
    float mul = cst[d], add = cst[128 + d];
#pragma unroll
    for (int r = 0; r < 4; r++) {
      float v = acc[n][r] * mul + add;
      v = v > 0.f ? v : 0.01f * v;
      putBf(sM, w * 16 + r0 + r, d, v);
    }
  }
  bf16x8 hA0 = fragM(sM, w * 16, 0, lane);   // own rows: same-wave RAW ok
  bf16x8 hA1 = fragM(sM, w * 16, 32, lane);
  bf16x8 hA2 = fragM(sM, w * 16, 64, lane);
  bf16x8 hA3 = fragM(sM, w * 16, 96, lane);
  BARRIER();

  // ---- Ph5: commit W1n-khi->B; accV = hA0@A(k0) + hA1@A(k32); issue W1s-klo
  stW64(sWB, t, sa, sb);
  stG64(wbf + 16384, 128, 0, t, sa, sb);
#pragma unroll
  for (int n = 0; n < 8; n++) acc[n] = zero;
#pragma unroll
  for (int n = 0; n < 8; n++) acc[n] = MFMA16(hA0, fragW64(sWA, n * 16, 0, lane), acc[n]);
#pragma unroll
  for (int n = 0; n < 8; n++) acc[n] = MFMA16(hA1, fragW64(sWA, n * 16, 32, lane), acc[n]);
  BARRIER();

  // ---- Ph6: commit W1s-klo->A; accV += hA2@B(k0) + hA3@B(k32); epiV V1^T -> sM; issue W1s-khi
  stW64(sWA, t, sa, sb);
  stG64(wbf + 16384, 128, 64, t, sa, sb);
#pragma unroll
  for (int n = 0; n < 8; n++) acc[n] = MFMA16(hA2, fragW64(sWB, n * 16, 0, lane), acc[n]);
#pragma unroll
  for (int n = 0; n < 8; n++) acc[n] = MFMA16(hA3, fragW64(sWB, n * 16, 32, lane), acc[n]);
#pragma unroll
  for (int n = 0; n < 8; n++) {
    bf16x4 q = {(__bf16)acc[n][0], (__bf16)acc[n][1], (__bf16)acc[n][2], (__bf16)acc[n][3]};
    int d = n * 16 + col;
    *(bf16x4*)((char*)sM + d * 256 + (((w * 16 + r0) * 2) ^ ((d & 7) << 4))) = q;
  }
  BARRIER();

  // ---- Ph7: commit W1s-khi->B; acc = Adj@V1 (last counts use)
  stW64(sWB, t, sa, sb);
#pragma unroll
  for (int n = 0; n < 8; n++) acc[n] = zero;
  for (int kb = 0; kb < 4; kb++) {
    bf16x8 aF = adjFrag(sC, invRow, w * 16, kb * 32, lane);
#pragma unroll
    for (int n = 0; n < 8; n++)
      acc[n] = MFMA16(aF, fragM(sM, n * 16, kb * 32, lane), acc[n]);
  }
  BARRIER();

  // ---- Ph8: zero pool/sums (counts dead); acc += hA0@A(k0)+hA1@A(k32) [W1s-klo]; issue Wa-klo; mwr
  if (t < 256) S3f[t] = 0.f;
  stG64(wbf + 49152, 128, 0, t, sa, sb);
  float mwr[4];
#pragma unroll
  for (int r = 0; r < 4; r++) mwr[r] = mwt[(size_t)gb * 128 + w * 16 + r0 + r];
#pragma unroll
  for (int n = 0; n < 8; n++) acc[n] = MFMA16(hA0, fragW64(sWA, n * 16, 0, lane), acc[n]);
#pragma unroll
  for (int n = 0; n < 8; n++) acc[n] = MFMA16(hA1, fragW64(sWA, n * 16, 32, lane), acc[n]);
  BARRIER();

  // ---- Ph9: commit Wa-klo->A; acc += hA2@B(k0)+hA3@B(k32) [W1s-khi]; BN1+mw epi -> h2 + pool; hA reload; issue Wa-khi
  stW64(sWA, t, sa, sb);
  stG64(wbf + 49152, 128, 64, t, sa, sb);
#pragma unroll
  for (int n = 0; n < 8; n++) acc[n] = MFMA16(hA2, fragW64(sWB, n * 16, 0, lane), acc[n]);
#pragma unroll
  for (int n = 0; n < 8; n++) acc[n] = MFMA16(hA3, fragW64(sWB, n * 16, 32, lane), acc[n]);
#pragma unroll
  for (int n = 0; n < 8; n++) {
    int d = n * 16 + col;
    float mul = cst[256 + d], add = cst[384 + d];
    float csum = 0.f;
#pragma unroll
    for (int r = 0; r < 4; r++) {
      float v = acc[n][r] * mul + add;
      v = v > 0.f ? v : 0.01f * v;
      v *= mwr[r];
      putBf(sM, w * 16 + r0 + r, d, v);
      csum += v;
    }
    csum += __shfl_xor(csum, 16);
    csum += __shfl_xor(csum, 32);
    if (lane < 16) atomicAdd(&S3f[d], csum);
  }
  hA0 = fragM(sM, w * 16, 0, lane);    // h2 own rows
  hA1 = fragM(sM, w * 16, 32, lane);
  hA2 = fragM(sM, w * 16, 64, lane);
  hA3 = fragM(sM, w * 16, 96, lane);
  BARRIER();

  // ---- Ph10: commit Wa-khi->B; accP = hA0@A(k0) + hA1@A(k32)
  stW64(sWB, t, sa, sb);
#pragma unroll
  for (int n = 0; n < 8; n++) acc[n] = zero;
#pragma unroll
  for (int n = 0; n < 8; n++) acc[n] = MFMA16(hA0, fragW64(sWA, n * 16, 0, lane), acc[n]);
#pragma unroll
  for (int n = 0; n < 8; n++) acc[n] = MFMA16(hA1, fragW64(sWA, n * 16, 32, lane), acc[n]);
  BARRIER();

  // ---- Ph11: accP += hA2@B(k0) + hA3@B(k32); +ba leaky -> p (over h2; h2 already pooled)
#pragma unroll
  for (int n = 0; n < 8; n++) acc[n] = MFMA16(hA2, fragW64(sWB, n * 16, 0, lane), acc[n]);
#pragma unroll
  for (int n = 0; n < 8; n++) acc[n] = MFMA16(hA3, fragW64(sWB, n * 16, 32, lane), acc[n]);
#pragma unroll
  for (int n = 0; n < 8; n++) {
    int d = n * 16 + col;
    float bav = ba[d];
#pragma unroll
    for (int r = 0; r < 4; r++) {
      float v = acc[n][r] + bav;
      v = v > 0.f ? v : 0.01f * v;
      putBf(sM, w * 16 + r0 + r, d, v);
    }
  }
  BARRIER();  // p complete for all rows

  // ---- Ph12: pair tiles -> sigmoid -> row/col sums (pair never stored)
  {
    f32x4 acc2[2] = {zero, zero};
    for (int kb = 0; kb < 128; kb += 32) {
#pragma unroll
      for (int i = 0; i < 2; i++) {
        int T = w * 2 + i;
        bf16x8 a = fragM(sM, (T >> 2) * 16, kb, lane);       // pA rows mb..mb+15
        bf16x8 b = fragM(sM, 64 + (T & 3) * 16, kb, lane);   // pB rows nb..nb+15
        acc2[i] = MFMA16(a, b, acc2[i]);
      }
    }
    float* sv1 = S3f + 128;
#pragma unroll
    for (int i = 0; i < 2; i++) {
      int T = w * 2 + i, mb = (T >> 2) * 16, nb = (T & 3) * 16;
      float s0 = 1.f / (1.f + __expf(-acc2[i][0]));
      float s1 = 1.f / (1.f + __expf(-acc2[i][1]));
      float s2 = 1.f / (1.f + __expf(-acc2[i][2]));
      float s3 = 1.f / (1.f + __expf(-acc2[i][3]));
      atomicAdd(&sv1[64 + nb + col], s0 + s1 + s2 + s3);
#pragma unroll
      for (int m = 1; m < 16; m <<= 1) {
        s0 += __shfl_xor(s0, m);
        s1 += __shfl_xor(s1, m);
        s2 += __shfl_xor(s2, m);
        s3 += __shfl_xor(s3, m);
      }
      if (col < 4) {
        float v = col == 0 ? s0 : (col == 1 ? s1 : (col == 2 ? s2 : s3));
        atomicAdd(&sv1[mb + r0 + col], v);
      }
    }
  }
  BARRIER();

  // ---- Ph13: delta pool: S3f[d] += sum_node u[node]*p[node][d]
  {
    int d = t & 127, q = t >> 7;
    float s = 0.f;
#pragma unroll
    for (int i = 0; i < 32; i++) {
      int node = q * 32 + i;
      float u = S3f[128 + node];
      float pv = bf2f(*(const unsigned short*)((const char*)sM + node * 256 +
                                               ((2 * d) ^ ((node & 7) << 4))));
      s += u * pv;
    }
    atomicAdd(&S3f[d], s);
  }
  BARRIER();

  // ---- Ph14: write pooled mean
  if (t < 128) pooled[(size_t)gb * 128 + t] = S3f[t] * (1.f / 128.f);
}

// ---------------- readout: r = leaky(leaky(pooled@Wr0+br0)@Wr1+br1)@Wout + bout ----------------
__global__ __launch_bounds__(128)
void readout_kernel(const float* __restrict__ pooled,
                    const float* __restrict__ wr0t, const float* __restrict__ br0,
                    const float* __restrict__ wr1t, const float* __restrict__ br1,
                    const float* __restrict__ Wout, const float* __restrict__ bout,
                    float* __restrict__ out) {
  __shared__ float pl[128], t1[128];
  __shared__ float sred[2];
  int g = blockIdx.x, t = threadIdx.x;
  pl[t] = pooled[(size_t)g * 128 + t];
  __syncthreads();
  {
    const float* row = wr0t + t * 128;
    float s = 0.f;
#pragma unroll 8
    for (int j = 0; j < 128; j++) s += pl[j] * row[j];
    s += br0[t];
    t1[t] = s > 0.f ? s : 0.01f * s;
  }
  __syncthreads();
  float v2;
  {
    const float* row = wr1t + t * 128;
    float s = 0.f;
#pragma unroll 8
    for (int j = 0; j < 128; j++) s += t1[j] * row[j];
    s += br1[t];
    s = s > 0.f ? s : 0.01f * s;
    v2 = s * Wout[t];
  }
#pragma unroll
  for (int m = 1; m < 64; m <<= 1) v2 += __shfl_xor(v2, m);
  if ((t & 63) == 0) sred[t >> 6] = v2;
  __syncthreads();
  if (t == 0) out[g] = sred[0] + sred[1] + bout[0];
}

extern "C" void kernel_launch(void* const* d_in, const int* in_sizes, int n_in,
                              void* d_out, int out_size, void* d_ws, size_t ws_size,
                              hipStream_t stream) {
  const float* x     = (const float*)d_in[0];
  const float* mwt   = (const float*)d_in[1];
  const float* Wc0s  = (const float*)d_in[2];
  const float* Wc0n  = (const float*)d_in[3];
  const float* bc0   = (const float*)d_in[4];
  const float* g0    = (const float*)d_in[5];
  const float* b0    = (const float*)d_in[6];
  const float* m0    = (const float*)d_in[7];
  const float* v0    = (const float*)d_in[8];
  const float* Wc1s  = (const float*)d_in[9];
  const float* Wc1n  = (const float*)d_in[10];
  const float* bc1   = (const float*)d_in[11];
  const float* g1    = (const float*)d_in[12];
  const float* b1    = (const float*)d_in[13];
  const float* m1    = (const float*)d_in[14];
  const float* v1    = (const float*)d_in[15];
  const float* Wa    = (const float*)d_in[16];
  const float* ba    = (const float*)d_in[17];
  const float* Wr0   = (const float*)d_in[18];
  const float* br0   = (const float*)d_in[19];
  const float* Wr1   = (const float*)d_in[20];
  const float* br1   = (const float*)d_in[21];
  const float* Wout  = (const float*)d_in[22];
  const float* bout  = (const float*)d_in[23];
  const int*   ei    = (const int*)d_in[24];

  unsigned short* wbf = (unsigned short*)d_ws;                 // 131072 B
  float* cst    = (float*)((char*)d_ws + 131072);              // 2048 B
  float* wr0t   = (float*)((char*)d_ws + 133120);              // 65536 B
  float* wr1t   = (float*)((char*)d_ws + 198656);              // 65536 B
  float* pooled = (float*)((char*)d_ws + 264192);              // 1048576 B

  prep_kernel<<<dim3(225), dim3(256), 0, stream>>>(Wc0s, Wc0n, Wc1s, Wc1n, Wa,
                                                   bc0, g0, b0, m0, v0,
                                                   bc1, g1, b1, m1, v1,
                                                   Wr0, Wr1, wbf, cst, wr0t, wr1t);
  gnn_fused<<<dim3(2048), dim3(512), 0, stream>>>(x, mwt, ei, wbf, cst, ba, pooled);
  readout_kernel<<<dim3(2048), dim3(128), 0, stream>>>(pooled, wr0t, br0, wr1t, br1,
                                                       Wout, bout, (float*)d_out);
}

// Round 14
// 159.667 us; speedup vs baseline: 1.1600x; 1.1600x over previous
//
#include <hip/hip_runtime.h>

#define N_EDGES_C 1048576

typedef __attribute__((ext_vector_type(8))) __bf16 bf16x8;
typedef __attribute__((ext_vector_type(4))) __bf16 bf16x4;
typedef __attribute__((ext_vector_type(4))) float f32x4;
typedef __attribute__((ext_vector_type(4))) unsigned int u32x4;

#define MFMA16(a,b,c) __builtin_amdgcn_mfma_f32_16x16x32_bf16((a),(b),(c),0,0,0)

// LDS-visible barrier that does NOT drain vmcnt: staged weight-chunk loads stay in flight.
#define BARRIER() do { asm volatile("s_waitcnt lgkmcnt(0)" ::: "memory"); \
                       __builtin_amdgcn_s_barrier(); \
                       asm volatile("" ::: "memory"); } while (0)

__device__ __forceinline__ unsigned short f2bf(float f) {
  unsigned int u = __builtin_bit_cast(unsigned int, f);
  u = (u + 0x7fffu + ((u >> 16) & 1u)) >> 16;
  return (unsigned short)u;
}
__device__ __forceinline__ float bf2f(unsigned short h) {
  unsigned int u = ((unsigned int)h) << 16;
  return __builtin_bit_cast(float, u);
}

// swizzled 128x128 bf16 LDS tile (row stride 256B, byte ^= (row&7)<<4)
__device__ __forceinline__ bf16x8 fragM(const unsigned short* sM, int row, int kb, int lane) {
  int r = row + (lane & 15);
  int cb = (kb + ((lane >> 4) << 3)) * 2;
  return *(const bf16x8*)((const char*)sM + r * 256 + (cb ^ ((r & 7) << 4)));
}
__device__ __forceinline__ void putBf(unsigned short* sM, int r, int c, float v) {
  *(__bf16*)((char*)sM + r * 256 + ((c * 2) ^ ((r & 7) << 4))) = (__bf16)v;
}
// Adj counts: u8 [128][128], row stride 128B, byte col ^= (row&7)<<3 (register-only decode)
__device__ __forceinline__ bf16x8 adjFrag(const unsigned char* sCc, float inv,
                                          int mBase, int kb, int lane) {
  int m = mBase + (lane & 15);
  int c = (kb + ((lane >> 4) << 3)) ^ ((m & 7) << 3);
  const unsigned int* p = (const unsigned int*)(sCc + m * 128 + c);
  unsigned int w0 = p[0], w1 = p[1];
  bf16x8 r;
#pragma unroll
  for (int i = 0; i < 4; i++) {
    r[i]     = (__bf16)((float)((w0 >> (8 * i)) & 0xffu) * inv);
    r[4 + i] = (__bf16)((float)((w1 >> (8 * i)) & 0xffu) * inv);
  }
  return r;
}

// K=32 weight chunk ring buffer: [128 rows][32 k] u16 = 8KB, row 64B.
// phys 16B slot = (ks + r + (r>>2)) & 3  -> conflict-free reads & writes.
__device__ __forceinline__ u32x4 stG32(const unsigned short* src, int KS, int ko, int t) {
  int row = t >> 2, ks = t & 3;
  return *(const u32x4*)(src + row * KS + ko + ks * 8);
}
__device__ __forceinline__ void stW32(unsigned short* buf, int t, u32x4 v) {
  int row = t >> 2, ks = t & 3;
  int slot = (ks + row + (row >> 2)) & 3;
  *(u32x4*)((char*)buf + row * 64 + slot * 16) = v;
}
__device__ __forceinline__ bf16x8 fragW32(const unsigned short* buf, int nc, int lane) {
  int r = nc + (lane & 15);
  int ks = lane >> 4;
  int slot = (ks + r + (r >> 2)) & 3;
  return *(const bf16x8*)((const char*)buf + r * 64 + slot * 16);
}

// ---------------- prep: bf16-transpose weights + fold BN + transpose readout W ----------------
__global__ void prep_kernel(const float* __restrict__ Wc0s, const float* __restrict__ Wc0n,
                            const float* __restrict__ Wc1s, const float* __restrict__ Wc1n,
                            const float* __restrict__ Wa,
                            const float* __restrict__ bc0, const float* __restrict__ g0,
                            const float* __restrict__ b0, const float* __restrict__ m0,
                            const float* __restrict__ v0,
                            const float* __restrict__ bc1, const float* __restrict__ g1,
                            const float* __restrict__ b1, const float* __restrict__ m1,
                            const float* __restrict__ v1,
                            const float* __restrict__ Wr0, const float* __restrict__ Wr1,
                            unsigned short* __restrict__ wbf, float* __restrict__ cst,
                            float* __restrict__ wr0t, float* __restrict__ wr1t) {
  int t = blockIdx.x * blockDim.x + threadIdx.x;
  if (t < 8192) {                       // 64x128 -> [d][f]
    int d = t >> 6, f = t & 63;
    wbf[t]        = f2bf(Wc0s[f * 128 + d]);
    wbf[8192 + t] = f2bf(Wc0n[f * 128 + d]);
  } else if (t < 24576) {               // 128x128 -> [d][k]
    int i = t - 8192;
    int d = i >> 7, k = i & 127;
    wbf[16384 + i] = f2bf(Wc1s[k * 128 + d]);
    wbf[32768 + i] = f2bf(Wc1n[k * 128 + d]);
    wbf[49152 + i] = f2bf(Wa[k * 128 + d]);
  } else if (t < 24704) {
    int d = t - 24576;
    float s0 = g0[d] * rsqrtf(v0[d] + 1e-5f);
    cst[d]       = s0;
    cst[128 + d] = (bc0[d] - m0[d]) * s0 + b0[d];
    float s1 = g1[d] * rsqrtf(v1[d] + 1e-5f);
    cst[256 + d] = s1;
    cst[384 + d] = (bc1[d] - m1[d]) * s1 + b1[d];
  } else if (t < 57472) {               // readout weights f32 transpose
    int i = t - 24704;
    int which = i >> 14;
    int k = i & 16383;
    int d = k >> 7, j = k & 127;
    float v = (which ? Wr1 : Wr0)[j * 128 + d];
    (which ? wr1t : wr0t)[k] = v;
  }
}

// ---------------- fused per-graph kernel: 1 block = 1 graph, ~75KB LDS, 2 blocks/CU ----------------
__global__ __launch_bounds__(512, 4)
void gnn_fused(const float* __restrict__ x, const float* __restrict__ mwt,
               const int* __restrict__ ei,
               const unsigned short* __restrict__ wbf, const float* __restrict__ cst,
               const float* __restrict__ ba,
               const float* __restrict__ wr0t, const float* __restrict__ br0,
               const float* __restrict__ wr1t, const float* __restrict__ br1,
               const float* __restrict__ Wout, const float* __restrict__ bout,
               float* __restrict__ out) {
  __shared__ unsigned short sM[128 * 128];   // 32KB: x / V^T / h / p (swizzled)
  __shared__ unsigned char  sC[128 * 128];   // 16KB: Adj u8 counts -> pool/sums/readout tmps
  __shared__ unsigned short sW[3][4096];     // 3 x 8KB weight chunk ring
  __shared__ float sDeg[128];
  __shared__ float sPool[128];
  __shared__ float sV1[128];                 // rowsum[0:64] / colsum[64:128]
  float* S3f = (float*)sC;                   // readout tmps after counts die

  const int gb = blockIdx.x;
  const int t = threadIdx.x;
  const int lane = t & 63;
  const int w = t >> 6;              // wave 0..7
  const int col = lane & 15;
  const int r0 = (lane >> 4) << 2;
  const f32x4 zero = {0.f, 0.f, 0.f, 0.f};
  u32x4 st0, st1;                    // in-flight stage regs

  // ---- Ph0: issue c0,c1,c2 + edge loads; zero; x -> sM
  st0 = stG32(wbf + 8192, 64, 0, t);   // c0 = W0n k0-31
  st1 = stG32(wbf + 8192, 64, 32, t);  // c1 = W0n k32-63
  u32x4 st2 = stG32(wbf, 64, 0, t);    // c2 = W0s k0-31
  int els, eld;
  {
    int e = gb * 512 + t;
    els = ei[e] & 127;
    eld = ei[N_EDGES_C + e] & 127;
  }
  {
    unsigned int* c32 = (unsigned int*)sC;
    for (int i = t; i < 4096; i += 512) c32[i] = 0u;
    if (t < 128) { sPool[t] = 0.f; sV1[t] = 0.f; sDeg[t] = 0.f; }
  }
  {
    const float4* xg = (const float4*)(x + (size_t)gb * 8192);
#pragma unroll
    for (int i = 0; i < 4; i++) {
      int vi = t + i * 512;
      float4 v = xg[vi];
      int node = vi >> 4;
      int f = (vi & 15) * 4;
      bf16x4 q = {(__bf16)v.x, (__bf16)v.y, (__bf16)v.z, (__bf16)v.w};
      *(bf16x4*)((char*)sM + node * 256 + ((f * 2) ^ ((node & 7) << 4))) = q;
    }
  }
  BARRIER();

  // ---- Ph1: hist + deg; commit c0,c1,c2; xA preload
  {
    int cb = els ^ ((eld & 7) << 3);
    int idx = eld * 128 + cb;
    atomicAdd((unsigned int*)(sC + (idx & ~3)), 1u << ((idx & 3) * 8));
    atomicAdd(&sDeg[eld], 1.f);
  }
  stW32(sW[0], t, st0);
  stW32(sW[1], t, st1);
  stW32(sW[2], t, st2);
  bf16x8 xA0 = fragM(sM, w * 16, 0, lane);
  bf16x8 xA1 = fragM(sM, w * 16, 32, lane);
  BARRIER();

  f32x4 acc[8];

  // ---- Ph2: issue c3,c4; V0 = xA0@c0 + xA1@c1; write V0^T
  st0 = stG32(wbf, 64, 32, t);           // c3 = W0s k32-63 -> ring0
  st1 = stG32(wbf + 32768, 128, 0, t);   // c4 = W1n k0 -> ring1
#pragma unroll
  for (int n = 0; n < 8; n++) acc[n] = zero;
#pragma unroll
  for (int n = 0; n < 8; n++) acc[n] = MFMA16(xA0, fragW32(sW[0], n * 16, lane), acc[n]);
#pragma unroll
  for (int n = 0; n < 8; n++) acc[n] = MFMA16(xA1, fragW32(sW[1], n * 16, lane), acc[n]);
#pragma unroll
  for (int n = 0; n < 8; n++) {  // V0^T[d][node]
    bf16x4 q = {(__bf16)acc[n][0], (__bf16)acc[n][1], (__bf16)acc[n][2], (__bf16)acc[n][3]};
    int d = n * 16 + col;
    *(bf16x4*)((char*)sM + d * 256 + (((w * 16 + r0) * 2) ^ ((d & 7) << 4))) = q;
  }
  BARRIER();

  // ---- Ph3: commit c3,c4; issue c5; acc = Adj@V0 + xA0@c2
  stW32(sW[0], t, st0);
  stW32(sW[1], t, st1);
  st0 = stG32(wbf + 32768, 128, 32, t);  // c5 = W1n k32 -> ring2
  const float invRow = 1.f / fmaxf(sDeg[w * 16 + col], 1.f);
#pragma unroll
  for (int n = 0; n < 8; n++) acc[n] = zero;
#pragma unroll
  for (int n = 0; n < 8; n++) acc[n] = MFMA16(xA0, fragW32(sW[2], n * 16, lane), acc[n]);
  for (int kb = 0; kb < 4; kb++) {
    bf16x8 aF = adjFrag(sC, invRow, w * 16, kb * 32, lane);
#pragma unroll
    for (int n = 0; n < 8; n++)
      acc[n] = MFMA16(aF, fragM(sM, n * 16, kb * 32, lane), acc[n]);
  }
  BARRIER();

  // ---- Ph4: commit c5; issue c6; acc += xA1@c3; BN0 epi -> h1; hA preload
  stW32(sW[2], t, st0);
  st1 = stG32(wbf + 32768, 128, 64, t);  // c6 = W1n k64 -> ring0
#pragma unroll
  for (int n = 0; n < 8; n++) acc[n] = MFMA16(xA1, fragW32(sW[0], n * 16, lane), acc[n]);
#pragma unroll
  for (int n = 0; n < 8; n++) {
    int d = n * 16 + col;
    float mul = cst[d], add = cst[128 + d];
#pragma unroll
    for (int r = 0; r < 4; r++) {
      float v = acc[n][r] * mul + add;
      v = v > 0.f ? v : 0.01f * v;
      putBf(sM, w * 16 + r0 + r, d, v);
    }
  }
  bf16x8 hA0 = fragM(sM, w * 16, 0, lane);   // own rows: same-wave RAW ok
  bf16x8 hA1 = fragM(sM, w * 16, 32, lane);
  bf16x8 hA2 = fragM(sM, w * 16, 64, lane);
  bf16x8 hA3 = fragM(sM, w * 16, 96, lane);
  BARRIER();

  // ---- Ph5: commit c6; issue c7; accV = hA0@c4
  stW32(sW[0], t, st1);
  st0 = stG32(wbf + 32768, 128, 96, t);  // c7 = W1n k96 -> ring1
#pragma unroll
  for (int n = 0; n < 8; n++) acc[n] = zero;
#pragma unroll
  for (int n = 0; n < 8; n++) acc[n] = MFMA16(hA0, fragW32(sW[1], n * 16, lane), acc[n]);
  BARRIER();

  // ---- Ph6: commit c7; issue c8; accV += hA1@c5
  stW32(sW[1], t, st0);
  st1 = stG32(wbf + 16384, 128, 0, t);   // c8 = W1s k0 -> ring2
#pragma unroll
  for (int n = 0; n < 8; n++) acc[n] = MFMA16(hA1, fragW32(sW[2], n * 16, lane), acc[n]);
  BARRIER();

  // ---- Ph7: commit c8; issue c9; accV += hA2@c6
  stW32(sW[2], t, st1);
  st0 = stG32(wbf + 16384, 128, 32, t);  // c9 = W1s k32 -> ring0
#pragma unroll
  for (int n = 0; n < 8; n++) acc[n] = MFMA16(hA2, fragW32(sW[0], n * 16, lane), acc[n]);
  BARRIER();

  // ---- Ph8: commit c9; issue c10; accV += hA3@c7; write V1^T
  stW32(sW[0], t, st0);
  st1 = stG32(wbf + 16384, 128, 64, t);  // c10 = W1s k64 -> ring1
#pragma unroll
  for (int n = 0; n < 8; n++) acc[n] = MFMA16(hA3, fragW32(sW[1], n * 16, lane), acc[n]);
#pragma unroll
  for (int n = 0; n < 8; n++) {
    bf16x4 q = {(__bf16)acc[n][0], (__bf16)acc[n][1], (__bf16)acc[n][2], (__bf16)acc[n][3]};
    int d = n * 16 + col;
    *(bf16x4*)((char*)sM + d * 256 + (((w * 16 + r0) * 2) ^ ((d & 7) << 4))) = q;
  }
  BARRIER();

  // ---- Ph9: commit c10; issue c11; acc = Adj@V1
  stW32(sW[1], t, st1);
  st0 = stG32(wbf + 16384, 128, 96, t);  // c11 = W1s k96 -> ring2
#pragma unroll
  for (int n = 0; n < 8; n++) acc[n] = zero;
  for (int kb = 0; kb < 4; kb++) {
    bf16x8 aF = adjFrag(sC, invRow, w * 16, kb * 32, lane);
#pragma unroll
    for (int n = 0; n < 8; n++)
      acc[n] = MFMA16(aF, fragM(sM, n * 16, kb * 32, lane), acc[n]);
  }
  BARRIER();

  // ---- Ph10: issue c12; acc += hA0@c8   (no commit: ring2 busy until c8 read)
  st1 = stG32(wbf + 49152, 128, 0, t);   // c12 = Wa k0 -> ring0
#pragma unroll
  for (int n = 0; n < 8; n++) acc[n] = MFMA16(hA0, fragW32(sW[2], n * 16, lane), acc[n]);
  BARRIER();

  // ---- Ph11: commit c11; issue c13; acc += hA1@c9
  stW32(sW[2], t, st0);
  st0 = stG32(wbf + 49152, 128, 32, t);  // c13 = Wa k32 -> ring1
#pragma unroll
  for (int n = 0; n < 8; n++) acc[n] = MFMA16(hA1, fragW32(sW[0], n * 16, lane), acc[n]);
  BARRIER();

  // ---- Ph12: commit c12; issue c14; acc += hA2@c10; mwr preload (1 phase ahead of use)
  stW32(sW[0], t, st1);
  st1 = stG32(wbf + 49152, 128, 64, t);  // c14 = Wa k64 -> ring2
  float mwr[4];
#pragma unroll
  for (int r = 0; r < 4; r++) mwr[r] = mwt[(size_t)gb * 128 + w * 16 + r0 + r];
#pragma unroll
  for (int n = 0; n < 8; n++) acc[n] = MFMA16(hA2, fragW32(sW[1], n * 16, lane), acc[n]);
  BARRIER();

  // ---- Ph13: commit c13; issue c15; acc += hA3@c11; BN1 epi -> h2 + pool; hA reload
  stW32(sW[1], t, st0);
  st0 = stG32(wbf + 49152, 128, 96, t);  // c15 = Wa k96 -> ring0
#pragma unroll
  for (int n = 0; n < 8; n++) acc[n] = MFMA16(hA3, fragW32(sW[2], n * 16, lane), acc[n]);
#pragma unroll
  for (int n = 0; n < 8; n++) {
    int d = n * 16 + col;
    float mul = cst[256 + d], add = cst[384 + d];
    float csum = 0.f;
#pragma unroll
    for (int r = 0; r < 4; r++) {
      float v = acc[n][r] * mul + add;
      v = v > 0.f ? v : 0.01f * v;
      v *= mwr[r];
      putBf(sM, w * 16 + r0 + r, d, v);
      csum += v;
    }
    csum += __shfl_xor(csum, 16);
    csum += __shfl_xor(csum, 32);
    if (lane < 16) atomicAdd(&sPool[d], csum);
  }
  hA0 = fragM(sM, w * 16, 0, lane);    // h2 own rows
  hA1 = fragM(sM, w * 16, 32, lane);
  hA2 = fragM(sM, w * 16, 64, lane);
  hA3 = fragM(sM, w * 16, 96, lane);
  BARRIER();

  // ---- Ph14: commit c14; accP = hA0@c12
  stW32(sW[2], t, st1);
#pragma unroll
  for (int n = 0; n < 8; n++) acc[n] = zero;
#pragma unroll
  for (int n = 0; n < 8; n++) acc[n] = MFMA16(hA0, fragW32(sW[0], n * 16, lane), acc[n]);
  BARRIER();

  // ---- Ph15: commit c15; accP += hA1@c13
  stW32(sW[0], t, st0);
#pragma unroll
  for (int n = 0; n < 8; n++) acc[n] = MFMA16(hA1, fragW32(sW[1], n * 16, lane), acc[n]);
  BARRIER();

  // ---- Ph16: accP += hA2@c14
#pragma unroll
  for (int n = 0; n < 8; n++) acc[n] = MFMA16(hA2, fragW32(sW[2], n * 16, lane), acc[n]);
  BARRIER();

  // ---- Ph17: accP += hA3@c15; +ba leaky -> p own rows
#pragma unroll
  for (int n = 0; n < 8; n++) acc[n] = MFMA16(hA3, fragW32(sW[0], n * 16, lane), acc[n]);
#pragma unroll
  for (int n = 0; n < 8; n++) {
    int d = n * 16 + col;
    float bav = ba[d];
#pragma unroll
    for (int r = 0; r < 4; r++) {
      float v = acc[n][r] + bav;
      v = v > 0.f ? v : 0.01f * v;
      putBf(sM, w * 16 + r0 + r, d, v);
    }
  }
  BARRIER();  // p complete for all rows

  // ---- Ph18: pair tiles -> sigmoid -> row/col sums (pair never stored)
  {
    f32x4 acc2[2] = {zero, zero};
    for (int kb = 0; kb < 128; kb += 32) {
#pragma unroll
      for (int i = 0; i < 2; i++) {
        int T = w * 2 + i;
        bf16x8 a = fragM(sM, (T >> 2) * 16, kb, lane);       // pA rows mb..mb+15
        bf16x8 b = fragM(sM, 64 + (T & 3) * 16, kb, lane);   // pB rows nb..nb+15
        acc2[i] = MFMA16(a, b, acc2[i]);
      }
    }
#pragma unroll
    for (int i = 0; i < 2; i++) {
      int T = w * 2 + i, mb = (T >> 2) * 16, nb = (T & 3) * 16;
      float s0 = 1.f / (1.f + __expf(-acc2[i][0]));
      float s1 = 1.f / (1.f + __expf(-acc2[i][1]));
      float s2 = 1.f / (1.f + __expf(-acc2[i][2]));
      float s3 = 1.f / (1.f + __expf(-acc2[i][3]));
      atomicAdd(&sV1[64 + nb + col], s0 + s1 + s2 + s3);
#pragma unroll
      for (int m = 1; m < 16; m <<= 1) {
        s0 += __shfl_xor(s0, m);
        s1 += __shfl_xor(s1, m);
        s2 += __shfl_xor(s2, m);
        s3 += __shfl_xor(s3, m);
      }
      if (col < 4) {
        float v = col == 0 ? s0 : (col == 1 ? s1 : (col == 2 ? s2 : s3));
        atomicAdd(&sV1[mb + r0 + col], v);
      }
    }
  }
  BARRIER();

  // ---- Ph19: delta pool: sPool[d] += sum_node u[node]*p[node][d]  (counts region dead now)
  {
    int d = t & 127, q = t >> 7;
    float s = 0.f;
#pragma unroll
    for (int i = 0; i < 32; i++) {
      int node = q * 32 + i;
      float u = sV1[node];
      float pv = bf2f(*(const unsigned short*)((const char*)sM + node * 256 +
                                               ((2 * d) ^ ((node & 7) << 4))));
      s += u * pv;
    }
    atomicAdd(&sPool[d], s);
  }
  BARRIER();

  // ---- Ph20: in-kernel readout (tmps in dead counts region S3f)
  if (t < 128) sPool[t] *= (1.f / 128.f);
  BARRIER();
  {
    int d = t >> 2, q = t & 3;
    const float* row = wr0t + d * 128 + q * 32;
    float s = 0.f;
#pragma unroll
    for (int j = 0; j < 32; j++) s += sPool[q * 32 + j] * row[j];
    s += __shfl_xor(s, 1);
    s += __shfl_xor(s, 2);
    if (q == 0) { s += br0[d]; S3f[256 + d] = s > 0.f ? s : 0.01f * s; }
  }
  BARRIER();
  {
    int d = t >> 2, q = t & 3;
    const float* row = wr1t + d * 128 + q * 32;
    float s = 0.f;
#pragma unroll
    for (int j = 0; j < 32; j++) s += S3f[256 + q * 32 + j] * row[j];
    s += __shfl_xor(s, 1);
    s += __shfl_xor(s, 2);
    if (q == 0) {
      s += br1[d];
      s = s > 0.f ? s : 0.01f * s;
      S3f[384 + d] = s * Wout[d];
    }
  }
  BARRIER();
  if (t < 64) {
    float v2 = S3f[384 + t] + S3f[384 + 64 + t];
#pragma unroll
    for (int m = 1; m < 64; m <<= 1) v2 += __shfl_xor(v2, m);
    if (t == 0) out[gb] = v2 + bout[0];
  }
}

extern "C" void kernel_launch(void* const* d_in, const int* in_sizes, int n_in,
                              void* d_out, int out_size, void* d_ws, size_t ws_size,
                              hipStream_t stream) {
  const float* x     = (const float*)d_in[0];
  const float* mwt   = (const float*)d_in[1];
  const float* Wc0s  = (const float*)d_in[2];
  const float* Wc0n  = (const float*)d_in[3];
  const float* bc0   = (const float*)d_in[4];
  const float* g0    = (const float*)d_in[5];
  const float* b0    = (const float*)d_in[6];
  const float* m0    = (const float*)d_in[7];
  const float* v0    = (const float*)d_in[8];
  const float* Wc1s  = (const float*)d_in[9];
  const float* Wc1n  = (const float*)d_in[10];
  const float* bc1   = (const float*)d_in[11];
  const float* g1    = (const float*)d_in[12];
  const float* b1    = (const float*)d_in[13];
  const float* m1    = (const float*)d_in[14];
  const float* v1    = (const float*)d_in[15];
  const float* Wa    = (const float*)d_in[16];
  const float* ba    = (const float*)d_in[17];
  const float* Wr0   = (const float*)d_in[18];
  const float* br0   = (const float*)d_in[19];
  const float* Wr1   = (const float*)d_in[20];
  const float* br1   = (const float*)d_in[21];
  const float* Wout  = (const float*)d_in[22];
  const float* bout  = (const float*)d_in[23];
  const int*   ei    = (const int*)d_in[24];

  unsigned short* wbf = (unsigned short*)d_ws;                 // 131072 B
  float* cst    = (float*)((char*)d_ws + 131072);              // 2048 B
  float* wr0t   = (float*)((char*)d_ws + 133120);              // 65536 B
  float* wr1t   = (float*)((char*)d_ws + 198656);              // 65536 B

  prep_kernel<<<dim3(225), dim3(256), 0, stream>>>(Wc0s, Wc0n, Wc1s, Wc1n, Wa,
                                                   bc0, g0, b0, m0, v0,
                                                   bc1, g1, b1, m1, v1,
                                                   Wr0, Wr1, wbf, cst, wr0t, wr1t);
  gnn_fused<<<dim3(2048), dim3(512), 0, stream>>>(x, mwt, ei, wbf, cst, ba,
                                                  wr0t, br0, wr1t, br1, Wout, bout,
                                                  (float*)d_out);
}

// Round 15
// 153.456 us; speedup vs baseline: 1.2069x; 1.0405x over previous
//
#include <hip/hip_runtime.h>

#define N_EDGES_C 1048576

typedef __attribute__((ext_vector_type(8))) __bf16 bf16x8;
typedef __attribute__((ext_vector_type(4))) __bf16 bf16x4;
typedef __attribute__((ext_vector_type(4))) float f32x4;
typedef __attribute__((ext_vector_type(4))) unsigned int u32x4;

#define MFMA16(a,b,c) __builtin_amdgcn_mfma_f32_16x16x32_bf16((a),(b),(c),0,0,0)

// LDS-visible barrier that does NOT drain vmcnt: staged weight-chunk loads stay in flight.
#define BARRIER() do { asm volatile("s_waitcnt lgkmcnt(0)" ::: "memory"); \
                       __builtin_amdgcn_s_barrier(); \
                       asm volatile("" ::: "memory"); } while (0)

__device__ __forceinline__ unsigned short f2bf(float f) {
  unsigned int u = __builtin_bit_cast(unsigned int, f);
  u = (u + 0x7fffu + ((u >> 16) & 1u)) >> 16;
  return (unsigned short)u;
}
__device__ __forceinline__ float bf2f(unsigned short h) {
  unsigned int u = ((unsigned int)h) << 16;
  return __builtin_bit_cast(float, u);
}

// swizzled 128x128 bf16 LDS tile (row stride 256B, byte ^= (row&7)<<4)
__device__ __forceinline__ bf16x8 fragM(const unsigned short* sM, int row, int kb, int lane) {
  int r = row + (lane & 15);
  int cb = (kb + ((lane >> 4) << 3)) * 2;
  return *(const bf16x8*)((const char*)sM + r * 256 + (cb ^ ((r & 7) << 4)));
}
__device__ __forceinline__ void putBf(unsigned short* sM, int r, int c, float v) {
  *(__bf16*)((char*)sM + r * 256 + ((c * 2) ^ ((r & 7) << 4))) = (__bf16)v;
}
// Adj counts: u8 [128][128], row stride 128B, byte col ^= (row&7)<<3 (register-only decode)
__device__ __forceinline__ bf16x8 adjFrag(const unsigned char* sCc, float inv,
                                          int mBase, int kb, int lane) {
  int m = mBase + (lane & 15);
  int c = (kb + ((lane >> 4) << 3)) ^ ((m & 7) << 3);
  const unsigned int* p = (const unsigned int*)(sCc + m * 128 + c);
  unsigned int w0 = p[0], w1 = p[1];
  bf16x8 r;
#pragma unroll
  for (int i = 0; i < 4; i++) {
    r[i]     = (__bf16)((float)((w0 >> (8 * i)) & 0xffu) * inv);
    r[4 + i] = (__bf16)((float)((w1 >> (8 * i)) & 0xffu) * inv);
  }
  return r;
}

// K=32 weight chunk ring buffer: [128 rows][32 k] u16 = 8KB, row 64B.
// phys 16B slot = (ks + r + (r>>2)) & 3  -> conflict-free reads & writes.
__device__ __forceinline__ u32x4 stG32(const unsigned short* src, int KS, int ko, int t) {
  int row = t >> 2, ks = t & 3;
  return *(const u32x4*)(src + row * KS + ko + ks * 8);
}
__device__ __forceinline__ void stW32(unsigned short* buf, int t, u32x4 v) {
  int row = t >> 2, ks = t & 3;
  int slot = (ks + row + (row >> 2)) & 3;
  *(u32x4*)((char*)buf + row * 64 + slot * 16) = v;
}
__device__ __forceinline__ bf16x8 fragW32(const unsigned short* buf, int nc, int lane) {
  int r = nc + (lane & 15);
  int ks = lane >> 4;
  int slot = (ks + r + (r >> 2)) & 3;
  return *(const bf16x8*)((const char*)buf + r * 64 + slot * 16);
}

// ---------------- prep: bf16-transpose weights + fold BN + transpose readout W ----------------
__global__ void prep_kernel(const float* __restrict__ Wc0s, const float* __restrict__ Wc0n,
                            const float* __restrict__ Wc1s, const float* __restrict__ Wc1n,
                            const float* __restrict__ Wa,
                            const float* __restrict__ bc0, const float* __restrict__ g0,
                            const float* __restrict__ b0, const float* __restrict__ m0,
                            const float* __restrict__ v0,
                            const float* __restrict__ bc1, const float* __restrict__ g1,
                            const float* __restrict__ b1, const float* __restrict__ m1,
                            const float* __restrict__ v1,
                            const float* __restrict__ Wr0, const float* __restrict__ Wr1,
                            unsigned short* __restrict__ wbf, float* __restrict__ cst,
                            float* __restrict__ wr0t, float* __restrict__ wr1t) {
  int t = blockIdx.x * blockDim.x + threadIdx.x;
  if (t < 8192) {                       // 64x128 -> [d][f]
    int d = t >> 6, f = t & 63;
    wbf[t]        = f2bf(Wc0s[f * 128 + d]);
    wbf[8192 + t] = f2bf(Wc0n[f * 128 + d]);
  } else if (t < 24576) {               // 128x128 -> [d][k]
    int i = t - 8192;
    int d = i >> 7, k = i & 127;
    wbf[16384 + i] = f2bf(Wc1s[k * 128 + d]);
    wbf[32768 + i] = f2bf(Wc1n[k * 128 + d]);
    wbf[49152 + i] = f2bf(Wa[k * 128 + d]);
  } else if (t < 24704) {
    int d = t - 24576;
    float s0 = g0[d] * rsqrtf(v0[d] + 1e-5f);
    cst[d]       = s0;
    cst[128 + d] = (bc0[d] - m0[d]) * s0 + b0[d];
    float s1 = g1[d] * rsqrtf(v1[d] + 1e-5f);
    cst[256 + d] = s1;
    cst[384 + d] = (bc1[d] - m1[d]) * s1 + b1[d];
  } else if (t < 57472) {               // readout weights f32 transpose
    int i = t - 24704;
    int which = i >> 14;
    int k = i & 16383;
    int d = k >> 7, j = k & 127;
    float v = (which ? Wr1 : Wr0)[j * 128 + d];
    (which ? wr1t : wr0t)[k] = v;
  }
}

// ---------------- fused per-graph kernel: 1 block = 1 graph, ~75KB LDS, 2 blocks/CU ----------------
__global__ __launch_bounds__(512, 4)
void gnn_fused(const float* __restrict__ x, const float* __restrict__ mwt,
               const int* __restrict__ ei,
               const unsigned short* __restrict__ wbf, const float* __restrict__ cst,
               const float* __restrict__ ba,
               const float* __restrict__ wr0t, const float* __restrict__ br0,
               const float* __restrict__ wr1t, const float* __restrict__ br1,
               const float* __restrict__ Wout, const float* __restrict__ bout,
               float* __restrict__ out) {
  __shared__ unsigned short sM[128 * 128];              // 32KB: x / V^T / h / p (swizzled)
  __shared__ __align__(16) unsigned char sC[128 * 128]; // 16KB: counts -> ring D + readout tmps
  __shared__ unsigned short sW[3][4096];                // 3 x 8KB weight chunk ring
  __shared__ float sDeg[128];
  __shared__ float sPool[128];
  __shared__ float sV1[128];                 // rowsum[0:64] / colsum[64:128]
  unsigned short* sD = (unsigned short*)sC;  // 4th ring buffer (after counts die, Ph10+)
  float* S3f = (float*)sC;                   // readout tmps after D dies

  const int gb = blockIdx.x;
  const int t = threadIdx.x;
  const int lane = t & 63;
  const int w = t >> 6;              // wave 0..7
  const int col = lane & 15;
  const int r0 = (lane >> 4) << 2;
  const f32x4 zero = {0.f, 0.f, 0.f, 0.f};
  u32x4 st0, st1;                    // in-flight stage regs

  // ---- Ph0: issue c0,c1,c2 + edge loads; zero; x -> sM
  st0 = stG32(wbf + 8192, 64, 0, t);   // c0 = W0n k0-31
  st1 = stG32(wbf + 8192, 64, 32, t);  // c1 = W0n k32-63
  u32x4 st2 = stG32(wbf, 64, 0, t);    // c2 = W0s k0-31
  int els, eld;
  {
    int e = gb * 512 + t;
    els = ei[e] & 127;
    eld = ei[N_EDGES_C + e] & 127;
  }
  {
    unsigned int* c32 = (unsigned int*)sC;
    for (int i = t; i < 4096; i += 512) c32[i] = 0u;
    if (t < 128) { sPool[t] = 0.f; sV1[t] = 0.f; sDeg[t] = 0.f; }
  }
  {
    const float4* xg = (const float4*)(x + (size_t)gb * 8192);
#pragma unroll
    for (int i = 0; i < 4; i++) {
      int vi = t + i * 512;
      float4 v = xg[vi];
      int node = vi >> 4;
      int f = (vi & 15) * 4;
      bf16x4 q = {(__bf16)v.x, (__bf16)v.y, (__bf16)v.z, (__bf16)v.w};
      *(bf16x4*)((char*)sM + node * 256 + ((f * 2) ^ ((node & 7) << 4))) = q;
    }
  }
  BARRIER();

  // ---- Ph1: hist + deg; commit c0,c1,c2; xA preload
  {
    int cb = els ^ ((eld & 7) << 3);
    int idx = eld * 128 + cb;
    atomicAdd((unsigned int*)(sC + (idx & ~3)), 1u << ((idx & 3) * 8));
    atomicAdd(&sDeg[eld], 1.f);
  }
  stW32(sW[0], t, st0);
  stW32(sW[1], t, st1);
  stW32(sW[2], t, st2);
  bf16x8 xA0 = fragM(sM, w * 16, 0, lane);
  bf16x8 xA1 = fragM(sM, w * 16, 32, lane);
  BARRIER();

  f32x4 acc[8];

  // ---- Ph2: issue c3,c4; V0 = xA0@c0 + xA1@c1; write V0^T
  st0 = stG32(wbf, 64, 32, t);           // c3 = W0s k32-63 -> ring0
  st1 = stG32(wbf + 32768, 128, 0, t);   // c4 = W1n k0 -> ring1
#pragma unroll
  for (int n = 0; n < 8; n++) acc[n] = zero;
#pragma unroll
  for (int n = 0; n < 8; n++) acc[n] = MFMA16(xA0, fragW32(sW[0], n * 16, lane), acc[n]);
#pragma unroll
  for (int n = 0; n < 8; n++) acc[n] = MFMA16(xA1, fragW32(sW[1], n * 16, lane), acc[n]);
#pragma unroll
  for (int n = 0; n < 8; n++) {  // V0^T[d][node]
    bf16x4 q = {(__bf16)acc[n][0], (__bf16)acc[n][1], (__bf16)acc[n][2], (__bf16)acc[n][3]};
    int d = n * 16 + col;
    *(bf16x4*)((char*)sM + d * 256 + (((w * 16 + r0) * 2) ^ ((d & 7) << 4))) = q;
  }
  BARRIER();

  // ---- Ph3: commit c3,c4; issue c5; acc = Adj@V0 + xA0@c2
  stW32(sW[0], t, st0);
  stW32(sW[1], t, st1);
  st0 = stG32(wbf + 32768, 128, 32, t);  // c5 = W1n k32 -> ring2
  const float invRow = 1.f / fmaxf(sDeg[w * 16 + col], 1.f);
#pragma unroll
  for (int n = 0; n < 8; n++) acc[n] = zero;
#pragma unroll
  for (int n = 0; n < 8; n++) acc[n] = MFMA16(xA0, fragW32(sW[2], n * 16, lane), acc[n]);
  for (int kb = 0; kb < 4; kb++) {
    bf16x8 aF = adjFrag(sC, invRow, w * 16, kb * 32, lane);
#pragma unroll
    for (int n = 0; n < 8; n++)
      acc[n] = MFMA16(aF, fragM(sM, n * 16, kb * 32, lane), acc[n]);
  }
  BARRIER();

  // ---- Ph4: commit c5; issue c6; acc += xA1@c3; BN0 epi -> h1; hA preload
  stW32(sW[2], t, st0);
  st1 = stG32(wbf + 32768, 128, 64, t);  // c6 = W1n k64 -> ring0
#pragma unroll
  for (int n = 0; n < 8; n++) acc[n] = MFMA16(xA1, fragW32(sW[0], n * 16, lane), acc[n]);
#pragma unroll
  for (int n = 0; n < 8; n++) {
    int d = n * 16 + col;
    float mul = cst[d], add = cst[128 + d];
#pragma unroll
    for (int r = 0; r < 4; r++) {
      float v = acc[n][r] * mul + add;
      v = v > 0.f ? v : 0.01f * v;
      putBf(sM, w * 16 + r0 + r, d, v);
    }
  }
  bf16x8 hA0 = fragM(sM, w * 16, 0, lane);   // own rows: same-wave RAW ok
  bf16x8 hA1 = fragM(sM, w * 16, 32, lane);
  bf16x8 hA2 = fragM(sM, w * 16, 64, lane);
  bf16x8 hA3 = fragM(sM, w * 16, 96, lane);
  BARRIER();

  // ---- Ph5: commit c6; issue c7; accV = hA0@c4
  stW32(sW[0], t, st1);
  st0 = stG32(wbf + 32768, 128, 96, t);  // c7 = W1n k96 -> ring1
#pragma unroll
  for (int n = 0; n < 8; n++) acc[n] = zero;
#pragma unroll
  for (int n = 0; n < 8; n++) acc[n] = MFMA16(hA0, fragW32(sW[1], n * 16, lane), acc[n]);
  BARRIER();

  // ---- Ph6: commit c7; issue c8; accV += hA1@c5
  stW32(sW[1], t, st0);
  st1 = stG32(wbf + 16384, 128, 0, t);   // c8 = W1s k0 -> ring2
#pragma unroll
  for (int n = 0; n < 8; n++) acc[n] = MFMA16(hA1, fragW32(sW[2], n * 16, lane), acc[n]);
  BARRIER();

  // ---- Ph7: commit c8; issue c9; accV += hA2@c6
  stW32(sW[2], t, st1);
  st0 = stG32(wbf + 16384, 128, 32, t);  // c9 = W1s k32 -> ring0
#pragma unroll
  for (int n = 0; n < 8; n++) acc[n] = MFMA16(hA2, fragW32(sW[0], n * 16, lane), acc[n]);
  BARRIER();

  // ---- Ph8: commit c9; issue c10; accV += hA3@c7; write V1^T
  stW32(sW[0], t, st0);
  st1 = stG32(wbf + 16384, 128, 64, t);  // c10 = W1s k64 -> ring1
#pragma unroll
  for (int n = 0; n < 8; n++) acc[n] = MFMA16(hA3, fragW32(sW[1], n * 16, lane), acc[n]);
#pragma unroll
  for (int n = 0; n < 8; n++) {
    bf16x4 q = {(__bf16)acc[n][0], (__bf16)acc[n][1], (__bf16)acc[n][2], (__bf16)acc[n][3]};
    int d = n * 16 + col;
    *(bf16x4*)((char*)sM + d * 256 + (((w * 16 + r0) * 2) ^ ((d & 7) << 4))) = q;
  }
  BARRIER();

  // ---- Ph9: commit c10; issue c11; acc = Adj@V1 (LAST read of counts)
  stW32(sW[1], t, st1);
  st0 = stG32(wbf + 16384, 128, 96, t);  // c11 = W1s k96
#pragma unroll
  for (int n = 0; n < 8; n++) acc[n] = zero;
  for (int kb = 0; kb < 4; kb++) {
    bf16x8 aF = adjFrag(sC, invRow, w * 16, kb * 32, lane);
#pragma unroll
    for (int n = 0; n < 8; n++)
      acc[n] = MFMA16(aF, fragM(sM, n * 16, kb * 32, lane), acc[n]);
  }
  BARRIER();

  // ---- Ph10: commit c11->D (counts dead); issue c12,c13; acc += hA0@c8 + hA1@c9; mwr
  stW32(sD, t, st0);
  st0 = stG32(wbf + 49152, 128, 0, t);   // c12 = Wa k0
  st1 = stG32(wbf + 49152, 128, 32, t);  // c13 = Wa k32
  float mwr[4];
#pragma unroll
  for (int r = 0; r < 4; r++) mwr[r] = mwt[(size_t)gb * 128 + w * 16 + r0 + r];
#pragma unroll
  for (int n = 0; n < 8; n++) acc[n] = MFMA16(hA0, fragW32(sW[2], n * 16, lane), acc[n]);
#pragma unroll
  for (int n = 0; n < 8; n++) acc[n] = MFMA16(hA1, fragW32(sW[0], n * 16, lane), acc[n]);
  BARRIER();

  // ---- Ph11: commit c12->ring2, c13->ring0; issue c14,c15; acc += hA2@c10 + hA3@c11(D);
  //            BN1 epi -> h2 + pool; hA reload
  stW32(sW[2], t, st0);
  stW32(sW[0], t, st1);
  st0 = stG32(wbf + 49152, 128, 64, t);  // c14 = Wa k64
  st1 = stG32(wbf + 49152, 128, 96, t);  // c15 = Wa k96
#pragma unroll
  for (int n = 0; n < 8; n++) acc[n] = MFMA16(hA2, fragW32(sW[1], n * 16, lane), acc[n]);
#pragma unroll
  for (int n = 0; n < 8; n++) acc[n] = MFMA16(hA3, fragW32(sD, n * 16, lane), acc[n]);
#pragma unroll
  for (int n = 0; n < 8; n++) {
    int d = n * 16 + col;
    float mul = cst[256 + d], add = cst[384 + d];
    float csum = 0.f;
#pragma unroll
    for (int r = 0; r < 4; r++) {
      float v = acc[n][r] * mul + add;
      v = v > 0.f ? v : 0.01f * v;
      v *= mwr[r];
      putBf(sM, w * 16 + r0 + r, d, v);
      csum += v;
    }
    csum += __shfl_xor(csum, 16);
    csum += __shfl_xor(csum, 32);
    if (lane < 16) atomicAdd(&sPool[d], csum);
  }
  hA0 = fragM(sM, w * 16, 0, lane);    // h2 own rows
  hA1 = fragM(sM, w * 16, 32, lane);
  hA2 = fragM(sM, w * 16, 64, lane);
  hA3 = fragM(sM, w * 16, 96, lane);
  BARRIER();

  // ---- Ph12: commit c14->ring1, c15->D; accP = hA0@c12 + hA1@c13
  stW32(sW[1], t, st0);
  stW32(sD, t, st1);
#pragma unroll
  for (int n = 0; n < 8; n++) acc[n] = zero;
#pragma unroll
  for (int n = 0; n < 8; n++) acc[n] = MFMA16(hA0, fragW32(sW[2], n * 16, lane), acc[n]);
#pragma unroll
  for (int n = 0; n < 8; n++) acc[n] = MFMA16(hA1, fragW32(sW[0], n * 16, lane), acc[n]);
  BARRIER();

  // ---- Ph13: accP += hA2@c14 + hA3@c15(D); +ba leaky -> p own rows
#pragma unroll
  for (int n = 0; n < 8; n++) acc[n] = MFMA16(hA2, fragW32(sW[1], n * 16, lane), acc[n]);
#pragma unroll
  for (int n = 0; n < 8; n++) acc[n] = MFMA16(hA3, fragW32(sD, n * 16, lane), acc[n]);
#pragma unroll
  for (int n = 0; n < 8; n++) {
    int d = n * 16 + col;
    float bav = ba[d];
#pragma unroll
    for (int r = 0; r < 4; r++) {
      float v = acc[n][r] + bav;
      v = v > 0.f ? v : 0.01f * v;
      putBf(sM, w * 16 + r0 + r, d, v);
    }
  }
  BARRIER();  // p complete for all rows

  // ---- Ph14: pair tiles -> sigmoid -> row/col sums (pair never stored)
  {
    f32x4 acc2[2] = {zero, zero};
    for (int kb = 0; kb < 128; kb += 32) {
#pragma unroll
      for (int i = 0; i < 2; i++) {
        int T = w * 2 + i;
        bf16x8 a = fragM(sM, (T >> 2) * 16, kb, lane);       // pA rows mb..mb+15
        bf16x8 b = fragM(sM, 64 + (T & 3) * 16, kb, lane);   // pB rows nb..nb+15
        acc2[i] = MFMA16(a, b, acc2[i]);
      }
    }
#pragma unroll
    for (int i = 0; i < 2; i++) {
      int T = w * 2 + i, mb = (T >> 2) * 16, nb = (T & 3) * 16;
      float s0 = 1.f / (1.f + __expf(-acc2[i][0]));
      float s1 = 1.f / (1.f + __expf(-acc2[i][1]));
      float s2 = 1.f / (1.f + __expf(-acc2[i][2]));
      float s3 = 1.f / (1.f + __expf(-acc2[i][3]));
      // colsum: reduce the 4 gq groups (16 rows) in-register first, then 16-lane atomics
      float sc = s0 + s1 + s2 + s3;
      sc += __shfl_xor(sc, 16);
      sc += __shfl_xor(sc, 32);
      if (lane < 16) atomicAdd(&sV1[64 + nb + col], sc);
      // rowsum: butterfly over the 16 col lanes
#pragma unroll
      for (int m = 1; m < 16; m <<= 1) {
        s0 += __shfl_xor(s0, m);
        s1 += __shfl_xor(s1, m);
        s2 += __shfl_xor(s2, m);
        s3 += __shfl_xor(s3, m);
      }
      if (col < 4) {
        float v = col == 0 ? s0 : (col == 1 ? s1 : (col == 2 ? s2 : s3));
        atomicAdd(&sV1[mb + r0 + col], v);
      }
    }
  }
  BARRIER();

  // ---- Ph15: delta pool: sPool[d] += sum_node u[node]*p[node][d]
  {
    int d = t & 127, q = t >> 7;
    float s = 0.f;
#pragma unroll
    for (int i = 0; i < 32; i++) {
      int node = q * 32 + i;
      float u = sV1[node];
      float pv = bf2f(*(const unsigned short*)((const char*)sM + node * 256 +
                                               ((2 * d) ^ ((node & 7) << 4))));
      s += u * pv;
    }
    atomicAdd(&sPool[d], s);
  }
  BARRIER();

  // ---- Ph16+: in-kernel readout (tmps in dead D region)
  if (t < 128) sPool[t] *= (1.f / 128.f);
  BARRIER();
  {
    int d = t >> 2, q = t & 3;
    const float* row = wr0t + d * 128 + q * 32;
    float s = 0.f;
#pragma unroll
    for (int j = 0; j < 32; j++) s += sPool[q * 32 + j] * row[j];
    s += __shfl_xor(s, 1);
    s += __shfl_xor(s, 2);
    if (q == 0) { s += br0[d]; S3f[256 + d] = s > 0.f ? s : 0.01f * s; }
  }
  BARRIER();
  {
    int d = t >> 2, q = t & 3;
    const float* row = wr1t + d * 128 + q * 32;
    float s = 0.f;
#pragma unroll
    for (int j = 0; j < 32; j++) s += S3f[256 + q * 32 + j] * row[j];
    s += __shfl_xor(s, 1);
    s += __shfl_xor(s, 2);
    if (q == 0) {
      s += br1[d];
      s = s > 0.f ? s : 0.01f * s;
      S3f[384 + d] = s * Wout[d];
    }
  }
  BARRIER();
  if (t < 64) {
    float v2 = S3f[384 + t] + S3f[384 + 64 + t];
#pragma unroll
    for (int m = 1; m < 64; m <<= 1) v2 += __shfl_xor(v2, m);
    if (t == 0) out[gb] = v2 + bout[0];
  }
}

extern "C" void kernel_launch(void* const* d_in, const int* in_sizes, int n_in,
                              void* d_out, int out_size, void* d_ws, size_t ws_size,
                              hipStream_t stream) {
  const float* x     = (const float*)d_in[0];
  const float* mwt   = (const float*)d_in[1];
  const float* Wc0s  = (const float*)d_in[2];
  const float* Wc0n  = (const float*)d_in[3];
  const float* bc0   = (const float*)d_in[4];
  const float* g0    = (const float*)d_in[5];
  const float* b0    = (const float*)d_in[6];
  const float* m0    = (const float*)d_in[7];
  const float* v0    = (const float*)d_in[8];
  const float* Wc1s  = (const float*)d_in[9];
  const float* Wc1n  = (const float*)d_in[10];
  const float* bc1   = (const float*)d_in[11];
  const float* g1    = (const float*)d_in[12];
  const float* b1    = (const float*)d_in[13];
  const float* m1    = (const float*)d_in[14];
  const float* v1    = (const float*)d_in[15];
  const float* Wa    = (const float*)d_in[16];
  const float* ba    = (const float*)d_in[17];
  const float* Wr0   = (const float*)d_in[18];
  const float* br0   = (const float*)d_in[19];
  const float* Wr1   = (const float*)d_in[20];
  const float* br1   = (const float*)d_in[21];
  const float* Wout  = (const float*)d_in[22];
  const float* bout  = (const float*)d_in[23];
  const int*   ei    = (const int*)d_in[24];

  unsigned short* wbf = (unsigned short*)d_ws;                 // 131072 B
  float* cst    = (float*)((char*)d_ws + 131072);              // 2048 B
  float* wr0t   = (float*)((char*)d_ws + 133120);              // 65536 B
  float* wr1t   = (float*)((char*)d_ws + 198656);              // 65536 B

  prep_kernel<<<dim3(225), dim3(256), 0, stream>>>(Wc0s, Wc0n, Wc1s, Wc1n, Wa,
                                                   bc0, g0, b0, m0, v0,
                                                   bc1, g1, b1, m1, v1,
                                                   Wr0, Wr1, wbf, cst, wr0t, wr1t);
  gnn_fused<<<dim3(2048), dim3(512), 0, stream>>>(x, mwt, ei, wbf, cst, ba,
                                                  wr0t, br0, wr1t, br1, Wout, bout,
                                                  (float*)d_out);
}

// Round 16
// 152.211 us; speedup vs baseline: 1.2168x; 1.0082x over previous
//
#include <hip/hip_runtime.h>

#define N_EDGES_C 1048576

typedef __attribute__((ext_vector_type(8))) __bf16 bf16x8;
typedef __attribute__((ext_vector_type(4))) __bf16 bf16x4;
typedef __attribute__((ext_vector_type(4))) float f32x4;
typedef __attribute__((ext_vector_type(4))) unsigned int u32x4;

#define MFMA16(a,b,c) __builtin_amdgcn_mfma_f32_16x16x32_bf16((a),(b),(c),0,0,0)

// LDS-visible barrier that does NOT drain vmcnt: staged weight-chunk loads stay in flight.
#define BARRIER() do { asm volatile("s_waitcnt lgkmcnt(0)" ::: "memory"); \
                       __builtin_amdgcn_s_barrier(); \
                       asm volatile("" ::: "memory"); } while (0)

__device__ __forceinline__ unsigned short f2bf(float f) {
  unsigned int u = __builtin_bit_cast(unsigned int, f);
  u = (u + 0x7fffu + ((u >> 16) & 1u)) >> 16;
  return (unsigned short)u;
}
__device__ __forceinline__ float bf2f(unsigned short h) {
  unsigned int u = ((unsigned int)h) << 16;
  return __builtin_bit_cast(float, u);
}

// swizzled 128x128 bf16 LDS tile (row stride 256B, byte ^= (row&7)<<4)
__device__ __forceinline__ bf16x8 fragM(const unsigned short* sM, int row, int kb, int lane) {
  int r = row + (lane & 15);
  int cb = (kb + ((lane >> 4) << 3)) * 2;
  return *(const bf16x8*)((const char*)sM + r * 256 + (cb ^ ((r & 7) << 4)));
}
__device__ __forceinline__ void putBf(unsigned short* sM, int r, int c, float v) {
  *(__bf16*)((char*)sM + r * 256 + ((c * 2) ^ ((r & 7) << 4))) = (__bf16)v;
}
// Adj counts: u8 [128][128], row stride 128B, byte col ^= (row&7)<<3 (register-only decode)
__device__ __forceinline__ bf16x8 adjFrag(const unsigned char* sCc, float inv,
                                          int mBase, int kb, int lane) {
  int m = mBase + (lane & 15);
  int c = (kb + ((lane >> 4) << 3)) ^ ((m & 7) << 3);
  const unsigned int* p = (const unsigned int*)(sCc + m * 128 + c);
  unsigned int w0 = p[0], w1 = p[1];
  bf16x8 r;
#pragma unroll
  for (int i = 0; i < 4; i++) {
    r[i]     = (__bf16)((float)((w0 >> (8 * i)) & 0xffu) * inv);
    r[4 + i] = (__bf16)((float)((w1 >> (8 * i)) & 0xffu) * inv);
  }
  return r;
}

// K=32 weight chunk ring buffer: [128 rows][32 k] u16 = 8KB, row 64B.
// phys 16B slot = (ks + r + (r>>2)) & 3  -> conflict-free reads & writes.
__device__ __forceinline__ u32x4 stG32(const unsigned short* src, int KS, int ko, int t) {
  int row = t >> 2, ks = t & 3;
  return *(const u32x4*)(src + row * KS + ko + ks * 8);
}
__device__ __forceinline__ void stW32(unsigned short* buf, int t, u32x4 v) {
  int row = t >> 2, ks = t & 3;
  int slot = (ks + row + (row >> 2)) & 3;
  *(u32x4*)((char*)buf + row * 64 + slot * 16) = v;
}
__device__ __forceinline__ bf16x8 fragW32(const unsigned short* buf, int nc, int lane) {
  int r = nc + (lane & 15);
  int ks = lane >> 4;
  int slot = (ks + r + (r >> 2)) & 3;
  return *(const bf16x8*)((const char*)buf + r * 64 + slot * 16);
}

// ---------------- prep: bf16-transpose weights + fold BN + transpose readout W ----------------
__global__ void prep_kernel(const float* __restrict__ Wc0s, const float* __restrict__ Wc0n,
                            const float* __restrict__ Wc1s, const float* __restrict__ Wc1n,
                            const float* __restrict__ Wa,
                            const float* __restrict__ bc0, const float* __restrict__ g0,
                            const float* __restrict__ b0, const float* __restrict__ m0,
                            const float* __restrict__ v0,
                            const float* __restrict__ bc1, const float* __restrict__ g1,
                            const float* __restrict__ b1, const float* __restrict__ m1,
                            const float* __restrict__ v1,
                            const float* __restrict__ Wr0, const float* __restrict__ Wr1,
                            unsigned short* __restrict__ wbf, float* __restrict__ cst,
                            float* __restrict__ wr0t, float* __restrict__ wr1t) {
  int t = blockIdx.x * blockDim.x + threadIdx.x;
  if (t < 8192) {                       // 64x128 -> [d][f]
    int d = t >> 6, f = t & 63;
    wbf[t]        = f2bf(Wc0s[f * 128 + d]);
    wbf[8192 + t] = f2bf(Wc0n[f * 128 + d]);
  } else if (t < 24576) {               // 128x128 -> [d][k]
    int i = t - 8192;
    int d = i >> 7, k = i & 127;
    wbf[16384 + i] = f2bf(Wc1s[k * 128 + d]);
    wbf[32768 + i] = f2bf(Wc1n[k * 128 + d]);
    wbf[49152 + i] = f2bf(Wa[k * 128 + d]);
  } else if (t < 24704) {
    int d = t - 24576;
    float s0 = g0[d] * rsqrtf(v0[d] + 1e-5f);
    cst[d]       = s0;
    cst[128 + d] = (bc0[d] - m0[d]) * s0 + b0[d];
    float s1 = g1[d] * rsqrtf(v1[d] + 1e-5f);
    cst[256 + d] = s1;
    cst[384 + d] = (bc1[d] - m1[d]) * s1 + b1[d];
  } else if (t < 57472) {               // readout weights f32 transpose
    int i = t - 24704;
    int which = i >> 14;
    int k = i & 16383;
    int d = k >> 7, j = k & 127;
    float v = (which ? Wr1 : Wr0)[j * 128 + d];
    (which ? wr1t : wr0t)[k] = v;
  }
}

// ---------------- fused per-graph kernel: 1 block = 1 graph, ~75KB LDS, 2 blocks/CU ----------------
__global__ __launch_bounds__(512, 4)
void gnn_fused(const float* __restrict__ x, const float* __restrict__ mwt,
               const int* __restrict__ ei,
               const unsigned short* __restrict__ wbf, const float* __restrict__ cst,
               const float* __restrict__ ba,
               const float* __restrict__ wr0t, const float* __restrict__ br0,
               const float* __restrict__ wr1t, const float* __restrict__ br1,
               const float* __restrict__ Wout, const float* __restrict__ bout,
               float* __restrict__ out) {
  __shared__ unsigned short sM[128 * 128];              // 32KB: x / V^T / h / p (swizzled)
  __shared__ __align__(16) unsigned char sC[128 * 128]; // 16KB: counts -> ring D + readout tmps
  __shared__ unsigned short sW[3][4096];                // 3 x 8KB weight chunk ring
  __shared__ float sDeg[128];
  __shared__ float sPool[128];
  __shared__ float sV1[128];                 // rowsum[0:64] / colsum[64:128]
  unsigned short* sD = (unsigned short*)sC;  // 4th ring buffer (after counts die, Ph10+)
  float* S3f = (float*)sC;                   // readout tmps after D dies

  const int gb = blockIdx.x;
  const int t = threadIdx.x;
  const int lane = t & 63;
  const int w = t >> 6;              // wave 0..7
  const int col = lane & 15;
  const int r0 = (lane >> 4) << 2;
  const f32x4 zero = {0.f, 0.f, 0.f, 0.f};
  u32x4 st0, st1;                    // in-flight stage regs

  // ---- Ph0: issue c0,c1,c2 + edge loads; zero; x -> sM
  st0 = stG32(wbf + 8192, 64, 0, t);   // c0 = W0n k0-31
  st1 = stG32(wbf + 8192, 64, 32, t);  // c1 = W0n k32-63
  u32x4 st2 = stG32(wbf, 64, 0, t);    // c2 = W0s k0-31
  int els, eld;
  {
    int e = gb * 512 + t;
    els = ei[e] & 127;
    eld = ei[N_EDGES_C + e] & 127;
  }
  {
    unsigned int* c32 = (unsigned int*)sC;
    for (int i = t; i < 4096; i += 512) c32[i] = 0u;
    if (t < 128) { sPool[t] = 0.f; sV1[t] = 0.f; sDeg[t] = 0.f; }
  }
  {
    const float4* xg = (const float4*)(x + (size_t)gb * 8192);
#pragma unroll
    for (int i = 0; i < 4; i++) {
      int vi = t + i * 512;
      float4 v = xg[vi];
      int node = vi >> 4;
      int f = (vi & 15) * 4;
      bf16x4 q = {(__bf16)v.x, (__bf16)v.y, (__bf16)v.z, (__bf16)v.w};
      *(bf16x4*)((char*)sM + node * 256 + ((f * 2) ^ ((node & 7) << 4))) = q;
    }
  }
  BARRIER();

  // ---- Ph1: hist + deg; commit c0,c1,c2; xA preload
  {
    int cb = els ^ ((eld & 7) << 3);
    int idx = eld * 128 + cb;
    atomicAdd((unsigned int*)(sC + (idx & ~3)), 1u << ((idx & 3) * 8));
    atomicAdd(&sDeg[eld], 1.f);
  }
  stW32(sW[0], t, st0);
  stW32(sW[1], t, st1);
  stW32(sW[2], t, st2);
  bf16x8 xA0 = fragM(sM, w * 16, 0, lane);
  bf16x8 xA1 = fragM(sM, w * 16, 32, lane);
  BARRIER();

  f32x4 acc[8];

  // ---- Ph2: issue c3,c4; V0 = xA0@c0 + xA1@c1; write V0^T
  st0 = stG32(wbf, 64, 32, t);           // c3 = W0s k32-63 -> ring0
  st1 = stG32(wbf + 32768, 128, 0, t);   // c4 = W1n k0 -> ring1
#pragma unroll
  for (int n = 0; n < 8; n++) acc[n] = zero;
#pragma unroll
  for (int n = 0; n < 8; n++) acc[n] = MFMA16(xA0, fragW32(sW[0], n * 16, lane), acc[n]);
#pragma unroll
  for (int n = 0; n < 8; n++) acc[n] = MFMA16(xA1, fragW32(sW[1], n * 16, lane), acc[n]);
#pragma unroll
  for (int n = 0; n < 8; n++) {  // V0^T[d][node]
    bf16x4 q = {(__bf16)acc[n][0], (__bf16)acc[n][1], (__bf16)acc[n][2], (__bf16)acc[n][3]};
    int d = n * 16 + col;
    *(bf16x4*)((char*)sM + d * 256 + (((w * 16 + r0) * 2) ^ ((d & 7) << 4))) = q;
  }
  BARRIER();

  // ---- Ph3: commit c3,c4; issue c5; acc = Adj@V0 + xA0@c2
  stW32(sW[0], t, st0);
  stW32(sW[1], t, st1);
  st0 = stG32(wbf + 32768, 128, 32, t);  // c5 = W1n k32 -> ring2
  const float invRow = 1.f / fmaxf(sDeg[w * 16 + col], 1.f);
#pragma unroll
  for (int n = 0; n < 8; n++) acc[n] = zero;
#pragma unroll
  for (int n = 0; n < 8; n++) acc[n] = MFMA16(xA0, fragW32(sW[2], n * 16, lane), acc[n]);
  for (int kb = 0; kb < 4; kb++) {
    bf16x8 aF = adjFrag(sC, invRow, w * 16, kb * 32, lane);
#pragma unroll
    for (int n = 0; n < 8; n++)
      acc[n] = MFMA16(aF, fragM(sM, n * 16, kb * 32, lane), acc[n]);
  }
  BARRIER();

  // ---- Ph4: commit c5; issue c6; acc += xA1@c3; BN0 epi -> h1; hA preload
  stW32(sW[2], t, st0);
  st1 = stG32(wbf + 32768, 128, 64, t);  // c6 = W1n k64 -> ring0
#pragma unroll
  for (int n = 0; n < 8; n++) acc[n] = MFMA16(xA1, fragW32(sW[0], n * 16, lane), acc[n]);
#pragma unroll
  for (int n = 0; n < 8; n++) {
    int d = n * 16 + col;
    float mul = cst[d], add = cst[128 + d];
#pragma unroll
    for (int r = 0; r < 4; r++) {
      float v = acc[n][r] * mul + add;
      v = v > 0.f ? v : 0.01f * v;
      putBf(sM, w * 16 + r0 + r, d, v);
    }
  }
  bf16x8 hA0 = fragM(sM, w * 16, 0, lane);   // own rows: same-wave RAW ok
  bf16x8 hA1 = fragM(sM, w * 16, 32, lane);
  bf16x8 hA2 = fragM(sM, w * 16, 64, lane);
  bf16x8 hA3 = fragM(sM, w * 16, 96, lane);
  BARRIER();

  // ---- Ph5: commit c6; issue c7; accV = hA0@c4
  stW32(sW[0], t, st1);
  st0 = stG32(wbf + 32768, 128, 96, t);  // c7 = W1n k96 -> ring1
#pragma unroll
  for (int n = 0; n < 8; n++) acc[n] = zero;
#pragma unroll
  for (int n = 0; n < 8; n++) acc[n] = MFMA16(hA0, fragW32(sW[1], n * 16, lane), acc[n]);
  BARRIER();

  // ---- Ph6: commit c7; issue c8; accV += hA1@c5
  stW32(sW[1], t, st0);
  st1 = stG32(wbf + 16384, 128, 0, t);   // c8 = W1s k0 -> ring2
#pragma unroll
  for (int n = 0; n < 8; n++) acc[n] = MFMA16(hA1, fragW32(sW[2], n * 16, lane), acc[n]);
  BARRIER();

  // ---- Ph7: commit c8; issue c9; accV += hA2@c6
  stW32(sW[2], t, st1);
  st0 = stG32(wbf + 16384, 128, 32, t);  // c9 = W1s k32 -> ring0
#pragma unroll
  for (int n = 0; n < 8; n++) acc[n] = MFMA16(hA2, fragW32(sW[0], n * 16, lane), acc[n]);
  BARRIER();

  // ---- Ph8: commit c9; issue c10; accV += hA3@c7; write V1^T
  stW32(sW[0], t, st0);
  st1 = stG32(wbf + 16384, 128, 64, t);  // c10 = W1s k64 -> ring1
#pragma unroll
  for (int n = 0; n < 8; n++) acc[n] = MFMA16(hA3, fragW32(sW[1], n * 16, lane), acc[n]);
#pragma unroll
  for (int n = 0; n < 8; n++) {
    bf16x4 q = {(__bf16)acc[n][0], (__bf16)acc[n][1], (__bf16)acc[n][2], (__bf16)acc[n][3]};
    int d = n * 16 + col;
    *(bf16x4*)((char*)sM + d * 256 + (((w * 16 + r0) * 2) ^ ((d & 7) << 4))) = q;
  }
  BARRIER();

  // ---- Ph9: commit c10; issue c11; acc = Adj@V1 (LAST read of counts)
  stW32(sW[1], t, st1);
  st0 = stG32(wbf + 16384, 128, 96, t);  // c11 = W1s k96
#pragma unroll
  for (int n = 0; n < 8; n++) acc[n] = zero;
  for (int kb = 0; kb < 4; kb++) {
    bf16x8 aF = adjFrag(sC, invRow, w * 16, kb * 32, lane);
#pragma unroll
    for (int n = 0; n < 8; n++)
      acc[n] = MFMA16(aF, fragM(sM, n * 16, kb * 32, lane), acc[n]);
  }
  BARRIER();

  // ---- Ph10: commit c11->D (counts dead); issue c12,c13; acc += hA0@c8 + hA1@c9; mwr
  stW32(sD, t, st0);
  st0 = stG32(wbf + 49152, 128, 0, t);   // c12 = Wa k0
  st1 = stG32(wbf + 49152, 128, 32, t);  // c13 = Wa k32
  float mwr[4];
#pragma unroll
  for (int r = 0; r < 4; r++) mwr[r] = mwt[(size_t)gb * 128 + w * 16 + r0 + r];
#pragma unroll
  for (int n = 0; n < 8; n++) acc[n] = MFMA16(hA0, fragW32(sW[2], n * 16, lane), acc[n]);
#pragma unroll
  for (int n = 0; n < 8; n++) acc[n] = MFMA16(hA1, fragW32(sW[0], n * 16, lane), acc[n]);
  BARRIER();

  // ---- Ph11: commit c12->ring2, c13->ring0; issue c14,c15; acc += hA2@c10 + hA3@c11(D);
  //            BN1 epi -> h2 + pool  (no hA reload: Ph12/13 read h2 from sM)
  stW32(sW[2], t, st0);
  stW32(sW[0], t, st1);
  st0 = stG32(wbf + 49152, 128, 64, t);  // c14 = Wa k64
  st1 = stG32(wbf + 49152, 128, 96, t);  // c15 = Wa k96
#pragma unroll
  for (int n = 0; n < 8; n++) acc[n] = MFMA16(hA2, fragW32(sW[1], n * 16, lane), acc[n]);
#pragma unroll
  for (int n = 0; n < 8; n++) acc[n] = MFMA16(hA3, fragW32(sD, n * 16, lane), acc[n]);
#pragma unroll
  for (int n = 0; n < 8; n++) {
    int d = n * 16 + col;
    float mul = cst[256 + d], add = cst[384 + d];
    float csum = 0.f;
#pragma unroll
    for (int r = 0; r < 4; r++) {
      float v = acc[n][r] * mul + add;
      v = v > 0.f ? v : 0.01f * v;
      v *= mwr[r];
      putBf(sM, w * 16 + r0 + r, d, v);
      csum += v;
    }
    csum += __shfl_xor(csum, 16);
    csum += __shfl_xor(csum, 32);
    if (lane < 16) atomicAdd(&sPool[d], csum);
  }
  BARRIER();

  // ---- Ph12: commit c14->ring1, c15->D; accP = h2@c12 + h2@c13 (h2 read from sM)
  stW32(sW[1], t, st0);
  stW32(sD, t, st1);
#pragma unroll
  for (int n = 0; n < 8; n++) acc[n] = zero;
  {
    bf16x8 h0 = fragM(sM, w * 16, 0, lane);
    bf16x8 h1 = fragM(sM, w * 16, 32, lane);
#pragma unroll
    for (int n = 0; n < 8; n++) acc[n] = MFMA16(h0, fragW32(sW[2], n * 16, lane), acc[n]);
#pragma unroll
    for (int n = 0; n < 8; n++) acc[n] = MFMA16(h1, fragW32(sW[0], n * 16, lane), acc[n]);
  }
  BARRIER();

  // ---- Ph13: accP += h2@c14 + h2@c15(D); +ba leaky -> p own rows (reads before writes, own rows)
  {
    bf16x8 h2f = fragM(sM, w * 16, 64, lane);
    bf16x8 h3f = fragM(sM, w * 16, 96, lane);
#pragma unroll
    for (int n = 0; n < 8; n++) acc[n] = MFMA16(h2f, fragW32(sW[1], n * 16, lane), acc[n]);
#pragma unroll
    for (int n = 0; n < 8; n++) acc[n] = MFMA16(h3f, fragW32(sD, n * 16, lane), acc[n]);
  }
#pragma unroll
  for (int n = 0; n < 8; n++) {
    int d = n * 16 + col;
    float bav = ba[d];
#pragma unroll
    for (int r = 0; r < 4; r++) {
      float v = acc[n][r] + bav;
      v = v > 0.f ? v : 0.01f * v;
      putBf(sM, w * 16 + r0 + r, d, v);
    }
  }
  BARRIER();  // p complete for all rows

  // ---- Ph14: pair tiles -> sigmoid -> row/col sums (pair never stored)
  {
    f32x4 acc2[2] = {zero, zero};
    for (int kb = 0; kb < 128; kb += 32) {
#pragma unroll
      for (int i = 0; i < 2; i++) {
        int T = w * 2 + i;
        bf16x8 a = fragM(sM, (T >> 2) * 16, kb, lane);       // pA rows mb..mb+15
        bf16x8 b = fragM(sM, 64 + (T & 3) * 16, kb, lane);   // pB rows nb..nb+15
        acc2[i] = MFMA16(a, b, acc2[i]);
      }
    }
#pragma unroll
    for (int i = 0; i < 2; i++) {
      int T = w * 2 + i, mb = (T >> 2) * 16, nb = (T & 3) * 16;
      float s0 = 1.f / (1.f + __expf(-acc2[i][0]));
      float s1 = 1.f / (1.f + __expf(-acc2[i][1]));
      float s2 = 1.f / (1.f + __expf(-acc2[i][2]));
      float s3 = 1.f / (1.f + __expf(-acc2[i][3]));
      // colsum: reduce the 4 gq groups (16 rows) in-register first, then 16-lane atomics
      float sc = s0 + s1 + s2 + s3;
      sc += __shfl_xor(sc, 16);
      sc += __shfl_xor(sc, 32);
      if (lane < 16) atomicAdd(&sV1[64 + nb + col], sc);
      // rowsum: butterfly over the 16 col lanes
#pragma unroll
      for (int m = 1; m < 16; m <<= 1) {
        s0 += __shfl_xor(s0, m);
        s1 += __shfl_xor(s1, m);
        s2 += __shfl_xor(s2, m);
        s3 += __shfl_xor(s3, m);
      }
      if (col < 4) {
        float v = col == 0 ? s0 : (col == 1 ? s1 : (col == 2 ? s2 : s3));
        atomicAdd(&sV1[mb + r0 + col], v);
      }
    }
  }
  BARRIER();

  // ---- Ph15: delta pool: sPool[d] += sum_node u[node]*p[node][d]; zero sOut (D dead)
  if (t == 0) S3f[512] = 0.f;
  {
    int d = t & 127, q = t >> 7;
    float s = 0.f;
#pragma unroll
    for (int i = 0; i < 32; i++) {
      int node = q * 32 + i;
      float u = sV1[node];
      float pv = bf2f(*(const unsigned short*)((const char*)sM + node * 256 +
                                               ((2 * d) ^ ((node & 7) << 4))));
      s += u * pv;
    }
    atomicAdd(&sPool[d], s);
  }
  BARRIER();

  // ---- Ph16: mv0 with folded 1/128 scale: t1 = leaky(pool/128 @ Wr0 + br0)
  {
    int d = t >> 2, q = t & 3;
    const float* row = wr0t + d * 128 + q * 32;
    float s = 0.f;
#pragma unroll
    for (int j = 0; j < 32; j++) s += sPool[q * 32 + j] * row[j];
    s += __shfl_xor(s, 1);
    s += __shfl_xor(s, 2);
    if (q == 0) {
      s = s * (1.f / 128.f) + br0[d];
      S3f[256 + d] = s > 0.f ? s : 0.01f * s;
    }
  }
  BARRIER();

  // ---- Ph17: mv1 + Wout dot via in-wave butterfly + one atomic per wave
  {
    int d = t >> 2, q = t & 3;
    const float* row = wr1t + d * 128 + q * 32;
    float s = 0.f;
#pragma unroll
    for (int j = 0; j < 32; j++) s += S3f[256 + q * 32 + j] * row[j];
    s += __shfl_xor(s, 1);
    s += __shfl_xor(s, 2);
    float v2 = 0.f;
    if (q == 0) {
      s += br1[d];
      s = s > 0.f ? s : 0.01f * s;
      v2 = s * Wout[d];
    }
#pragma unroll
    for (int m = 1; m < 64; m <<= 1) v2 += __shfl_xor(v2, m);
    if (lane == 0) atomicAdd(&S3f[512], v2);
  }
  BARRIER();
  if (t == 0) out[gb] = S3f[512] + bout[0];
}

extern "C" void kernel_launch(void* const* d_in, const int* in_sizes, int n_in,
                              void* d_out, int out_size, void* d_ws, size_t ws_size,
                              hipStream_t stream) {
  const float* x     = (const float*)d_in[0];
  const float* mwt   = (const float*)d_in[1];
  const float* Wc0s  = (const float*)d_in[2];
  const float* Wc0n  = (const float*)d_in[3];
  const float* bc0   = (const float*)d_in[4];
  const float* g0    = (const float*)d_in[5];
  const float* b0    = (const float*)d_in[6];
  const float* m0    = (const float*)d_in[7];
  const float* v0    = (const float*)d_in[8];
  const float* Wc1s  = (const float*)d_in[9];
  const float* Wc1n  = (const float*)d_in[10];
  const float* bc1   = (const float*)d_in[11];
  const float* g1    = (const float*)d_in[12];
  const float* b1    = (const float*)d_in[13];
  const float* m1    = (const float*)d_in[14];
  const float* v1    = (const float*)d_in[15];
  const float* Wa    = (const float*)d_in[16];
  const float* ba    = (const float*)d_in[17];
  const float* Wr0   = (const float*)d_in[18];
  const float* br0   = (const float*)d_in[19];
  const float* Wr1   = (const float*)d_in[20];
  const float* br1   = (const float*)d_in[21];
  const float* Wout  = (const float*)d_in[22];
  const float* bout  = (const float*)d_in[23];
  const int*   ei    = (const int*)d_in[24];

  unsigned short* wbf = (unsigned short*)d_ws;                 // 131072 B
  float* cst    = (float*)((char*)d_ws + 131072);              // 2048 B
  float* wr0t   = (float*)((char*)d_ws + 133120);              // 65536 B
  float* wr1t   = (float*)((char*)d_ws + 198656);              // 65536 B

  prep_kernel<<<dim3(225), dim3(256), 0, stream>>>(Wc0s, Wc0n, Wc1s, Wc1n, Wa,
                                                   bc0, g0, b0, m0, v0,
                                                   bc1, g1, b1, m1, v1,
                                                   Wr0, Wr1, wbf, cst, wr0t, wr1t);
  gnn_fused<<<dim3(2048), dim3(512), 0, stream>>>(x, mwt, ei, wbf, cst, ba,
                                                  wr0t, br0, wr1t, br1, Wout, bout,
                                                  (float*)d_out);
}

// Round 17
// 151.594 us; speedup vs baseline: 1.2218x; 1.0041x over previous
//
#include <hip/hip_runtime.h>

#define N_EDGES_C 1048576

typedef __attribute__((ext_vector_type(8))) __bf16 bf16x8;
typedef __attribute__((ext_vector_type(4))) __bf16 bf16x4;
typedef __attribute__((ext_vector_type(4))) float f32x4;
typedef __attribute__((ext_vector_type(4))) unsigned int u32x4;

#define MFMA16(a,b,c) __builtin_amdgcn_mfma_f32_16x16x32_bf16((a),(b),(c),0,0,0)

// LDS-visible barrier that does NOT drain vmcnt: staged weight-chunk loads stay in flight.
#define BARRIER() do { asm volatile("s_waitcnt lgkmcnt(0)" ::: "memory"); \
                       __builtin_amdgcn_s_barrier(); \
                       asm volatile("" ::: "memory"); } while (0)

__device__ __forceinline__ unsigned short f2bf(float f) {
  unsigned int u = __builtin_bit_cast(unsigned int, f);
  u = (u + 0x7fffu + ((u >> 16) & 1u)) >> 16;
  return (unsigned short)u;
}
__device__ __forceinline__ float bf2f(unsigned short h) {
  unsigned int u = ((unsigned int)h) << 16;
  return __builtin_bit_cast(float, u);
}

// swizzled 128x128 bf16 LDS tile (row stride 256B, byte ^= (row&7)<<4)
__device__ __forceinline__ bf16x8 fragM(const unsigned short* sM, int row, int kb, int lane) {
  int r = row + (lane & 15);
  int cb = (kb + ((lane >> 4) << 3)) * 2;
  return *(const bf16x8*)((const char*)sM + r * 256 + (cb ^ ((r & 7) << 4)));
}
__device__ __forceinline__ void putBf(unsigned short* sM, int r, int c, float v) {
  *(__bf16*)((char*)sM + r * 256 + ((c * 2) ^ ((r & 7) << 4))) = (__bf16)v;
}
// Adj counts: u8 [128][128], row stride 128B, byte col ^= (row&7)<<3 (register-only decode)
__device__ __forceinline__ bf16x8 adjFrag(const unsigned char* sCc, float inv,
                                          int mBase, int kb, int lane) {
  int m = mBase + (lane & 15);
  int c = (kb + ((lane >> 4) << 3)) ^ ((m & 7) << 3);
  const unsigned int* p = (const unsigned int*)(sCc + m * 128 + c);
  unsigned int w0 = p[0], w1 = p[1];
  bf16x8 r;
#pragma unroll
  for (int i = 0; i < 4; i++) {
    r[i]     = (__bf16)((float)((w0 >> (8 * i)) & 0xffu) * inv);
    r[4 + i] = (__bf16)((float)((w1 >> (8 * i)) & 0xffu) * inv);
  }
  return r;
}

// K=32 weight chunk ring buffer: [128 rows][32 k] u16 = 8KB, row 64B.
// phys 16B slot = (ks + r + (r>>2)) & 3  -> conflict-free reads & writes.
__device__ __forceinline__ u32x4 stG32(const unsigned short* src, int KS, int ko, int t) {
  int row = t >> 2, ks = t & 3;
  return *(const u32x4*)(src + row * KS + ko + ks * 8);
}
__device__ __forceinline__ void stW32(unsigned short* buf, int t, u32x4 v) {
  int row = t >> 2, ks = t & 3;
  int slot = (ks + row + (row >> 2)) & 3;
  *(u32x4*)((char*)buf + row * 64 + slot * 16) = v;
}
__device__ __forceinline__ bf16x8 fragW32(const unsigned short* buf, int nc, int lane) {
  int r = nc + (lane & 15);
  int ks = lane >> 4;
  int slot = (ks + r + (r >> 2)) & 3;
  return *(const bf16x8*)((const char*)buf + r * 64 + slot * 16);
}

// ---------------- prep: bf16-transpose weights + fold BN + transpose readout W ----------------
__global__ void prep_kernel(const float* __restrict__ Wc0s, const float* __restrict__ Wc0n,
                            const float* __restrict__ Wc1s, const float* __restrict__ Wc1n,
                            const float* __restrict__ Wa,
                            const float* __restrict__ bc0, const float* __restrict__ g0,
                            const float* __restrict__ b0, const float* __restrict__ m0,
                            const float* __restrict__ v0,
                            const float* __restrict__ bc1, const float* __restrict__ g1,
                            const float* __restrict__ b1, const float* __restrict__ m1,
                            const float* __restrict__ v1,
                            const float* __restrict__ Wr0, const float* __restrict__ Wr1,
                            unsigned short* __restrict__ wbf, float* __restrict__ cst,
                            float* __restrict__ wr0t, float* __restrict__ wr1t) {
  int t = blockIdx.x * blockDim.x + threadIdx.x;
  if (t < 8192) {                       // 64x128 -> [d][f]
    int d = t >> 6, f = t & 63;
    wbf[t]        = f2bf(Wc0s[f * 128 + d]);
    wbf[8192 + t] = f2bf(Wc0n[f * 128 + d]);
  } else if (t < 24576) {               // 128x128 -> [d][k]
    int i = t - 8192;
    int d = i >> 7, k = i & 127;
    wbf[16384 + i] = f2bf(Wc1s[k * 128 + d]);
    wbf[32768 + i] = f2bf(Wc1n[k * 128 + d]);
    wbf[49152 + i] = f2bf(Wa[k * 128 + d]);
  } else if (t < 24704) {
    int d = t - 24576;
    float s0 = g0[d] * rsqrtf(v0[d] + 1e-5f);
    cst[d]       = s0;
    cst[128 + d] = (bc0[d] - m0[d]) * s0 + b0[d];
    float s1 = g1[d] * rsqrtf(v1[d] + 1e-5f);
    cst[256 + d] = s1;
    cst[384 + d] = (bc1[d] - m1[d]) * s1 + b1[d];
  } else if (t < 57472) {               // readout weights f32 transpose
    int i = t - 24704;
    int which = i >> 14;
    int k = i & 16383;
    int d = k >> 7, j = k & 127;
    float v = (which ? Wr1 : Wr0)[j * 128 + d];
    (which ? wr1t : wr0t)[k] = v;
  }
}

// ---------------- fused per-graph kernel: 1 block = 1 graph, ~75KB LDS, 2 blocks/CU ----------------
// Chunks: c0/c1=W0n k0/k32, c2/c3=W0s k0/k32, c4-7=W1n k0/32/64/96,
//         c8-11=W1s k0/32/64/96, c12-15=Wa k0/32/64/96.
__global__ __launch_bounds__(512, 4)
void gnn_fused(const float* __restrict__ x, const float* __restrict__ mwt,
               const int* __restrict__ ei,
               const unsigned short* __restrict__ wbf, const float* __restrict__ cst,
               const float* __restrict__ ba,
               const float* __restrict__ wr0t, const float* __restrict__ br0,
               const float* __restrict__ wr1t, const float* __restrict__ br1,
               const float* __restrict__ Wout, const float* __restrict__ bout,
               float* __restrict__ out) {
  __shared__ unsigned short sM[128 * 128];              // 32KB: x / V^T / h / p (swizzled)
  __shared__ __align__(16) unsigned char sC[128 * 128]; // 16KB: counts -> ring D + readout tmps
  __shared__ unsigned short sW[3][4096];                // 3 x 8KB weight chunk ring
  __shared__ float sDeg[128];
  __shared__ float sPool[128];
  __shared__ float sV1[128];                 // rowsum[0:64] / colsum[64:128]
  unsigned short* sD = (unsigned short*)sC;  // 4th ring buffer (after counts die)
  float* S3f = (float*)sC;                   // readout tmps after D dies

  const int gb = blockIdx.x;
  const int t = threadIdx.x;
  const int lane = t & 63;
  const int w = t >> 6;              // wave 0..7
  const int col = lane & 15;
  const int r0 = (lane >> 4) << 2;
  const f32x4 zero = {0.f, 0.f, 0.f, 0.f};
  u32x4 st0, st1;                    // in-flight stage regs

  // ---- Ph0: issue c0,c1,c2 + edge loads; zero; x -> sM
  st0 = stG32(wbf + 8192, 64, 0, t);   // c0
  st1 = stG32(wbf + 8192, 64, 32, t);  // c1
  u32x4 st2 = stG32(wbf, 64, 0, t);    // c2
  int els, eld;
  {
    int e = gb * 512 + t;
    els = ei[e] & 127;
    eld = ei[N_EDGES_C + e] & 127;
  }
  {
    unsigned int* c32 = (unsigned int*)sC;
    for (int i = t; i < 4096; i += 512) c32[i] = 0u;
    if (t < 128) { sPool[t] = 0.f; sV1[t] = 0.f; sDeg[t] = 0.f; }
  }
  {
    const float4* xg = (const float4*)(x + (size_t)gb * 8192);
#pragma unroll
    for (int i = 0; i < 4; i++) {
      int vi = t + i * 512;
      float4 v = xg[vi];
      int node = vi >> 4;
      int f = (vi & 15) * 4;
      bf16x4 q = {(__bf16)v.x, (__bf16)v.y, (__bf16)v.z, (__bf16)v.w};
      *(bf16x4*)((char*)sM + node * 256 + ((f * 2) ^ ((node & 7) << 4))) = q;
    }
  }
  BARRIER();

  // ---- Ph1: hist + deg; commit c0->r0, c1->r1, c2->r2; xA preload
  {
    int cb = els ^ ((eld & 7) << 3);
    int idx = eld * 128 + cb;
    atomicAdd((unsigned int*)(sC + (idx & ~3)), 1u << ((idx & 3) * 8));
    atomicAdd(&sDeg[eld], 1.f);
  }
  stW32(sW[0], t, st0);
  stW32(sW[1], t, st1);
  stW32(sW[2], t, st2);
  bf16x8 xA0 = fragM(sM, w * 16, 0, lane);
  bf16x8 xA1 = fragM(sM, w * 16, 32, lane);
  BARRIER();

  f32x4 acc[8];

  // ---- Ph2: issue c3,c4; V0 = xA0@c0 + xA1@c1; write V0^T
  st0 = stG32(wbf, 64, 32, t);           // c3
  st1 = stG32(wbf + 32768, 128, 0, t);   // c4
#pragma unroll
  for (int n = 0; n < 8; n++) acc[n] = zero;
#pragma unroll
  for (int n = 0; n < 8; n++) acc[n] = MFMA16(xA0, fragW32(sW[0], n * 16, lane), acc[n]);
#pragma unroll
  for (int n = 0; n < 8; n++) acc[n] = MFMA16(xA1, fragW32(sW[1], n * 16, lane), acc[n]);
#pragma unroll
  for (int n = 0; n < 8; n++) {  // V0^T[d][node]
    bf16x4 q = {(__bf16)acc[n][0], (__bf16)acc[n][1], (__bf16)acc[n][2], (__bf16)acc[n][3]};
    int d = n * 16 + col;
    *(bf16x4*)((char*)sM + d * 256 + (((w * 16 + r0) * 2) ^ ((d & 7) << 4))) = q;
  }
  BARRIER();

  // ---- Ph3: commit c3->r0, c4->r1; issue c5; acc = Adj@V0 + xA0@c2
  stW32(sW[0], t, st0);
  stW32(sW[1], t, st1);
  st0 = stG32(wbf + 32768, 128, 32, t);  // c5
  const float invRow = 1.f / fmaxf(sDeg[w * 16 + col], 1.f);
#pragma unroll
  for (int n = 0; n < 8; n++) acc[n] = zero;
#pragma unroll
  for (int n = 0; n < 8; n++) acc[n] = MFMA16(xA0, fragW32(sW[2], n * 16, lane), acc[n]);
  for (int kb = 0; kb < 4; kb++) {
    bf16x8 aF = adjFrag(sC, invRow, w * 16, kb * 32, lane);
#pragma unroll
    for (int n = 0; n < 8; n++)
      acc[n] = MFMA16(aF, fragM(sM, n * 16, kb * 32, lane), acc[n]);
  }
  BARRIER();

  // ---- Ph4: commit c5->r2; issue c6; acc += xA1@c3; BN0 epi -> h1; hA preload
  stW32(sW[2], t, st0);
  st1 = stG32(wbf + 32768, 128, 64, t);  // c6
#pragma unroll
  for (int n = 0; n < 8; n++) acc[n] = MFMA16(xA1, fragW32(sW[0], n * 16, lane), acc[n]);
#pragma unroll
  for (int n = 0; n < 8; n++) {
    int d = n * 16 + col;
    float mul = cst[d], add = cst[128 + d];
#pragma unroll
    for (int r = 0; r < 4; r++) {
      float v = acc[n][r] * mul + add;
      v = v > 0.f ? v : 0.01f * v;
      putBf(sM, w * 16 + r0 + r, d, v);
    }
  }
  bf16x8 hA0 = fragM(sM, w * 16, 0, lane);   // own rows: same-wave RAW ok
  bf16x8 hA1 = fragM(sM, w * 16, 32, lane);
  bf16x8 hA2 = fragM(sM, w * 16, 64, lane);
  bf16x8 hA3 = fragM(sM, w * 16, 96, lane);
  BARRIER();

  // ---- Ph5: commit c6->r0; issue c7,c8; accV = hA0@c4 + hA1@c5  [16 MFMA]
  stW32(sW[0], t, st1);
  st0 = stG32(wbf + 32768, 128, 96, t);  // c7
  st1 = stG32(wbf + 16384, 128, 0, t);   // c8
#pragma unroll
  for (int n = 0; n < 8; n++) acc[n] = zero;
#pragma unroll
  for (int n = 0; n < 8; n++) acc[n] = MFMA16(hA0, fragW32(sW[1], n * 16, lane), acc[n]);
#pragma unroll
  for (int n = 0; n < 8; n++) acc[n] = MFMA16(hA1, fragW32(sW[2], n * 16, lane), acc[n]);
  BARRIER();

  // ---- Ph6: commit c7->r1, c8->r2; issue c9; accV += hA2@c6
  stW32(sW[1], t, st0);
  stW32(sW[2], t, st1);
  st0 = stG32(wbf + 16384, 128, 32, t);  // c9
#pragma unroll
  for (int n = 0; n < 8; n++) acc[n] = MFMA16(hA2, fragW32(sW[0], n * 16, lane), acc[n]);
  BARRIER();

  // ---- Ph7: commit c9->r0; issue c10,c11; accV += hA3@c7; write V1^T
  stW32(sW[0], t, st0);
  st0 = stG32(wbf + 16384, 128, 64, t);  // c10
  st1 = stG32(wbf + 16384, 128, 96, t);  // c11
#pragma unroll
  for (int n = 0; n < 8; n++) acc[n] = MFMA16(hA3, fragW32(sW[1], n * 16, lane), acc[n]);
#pragma unroll
  for (int n = 0; n < 8; n++) {
    bf16x4 q = {(__bf16)acc[n][0], (__bf16)acc[n][1], (__bf16)acc[n][2], (__bf16)acc[n][3]};
    int d = n * 16 + col;
    *(bf16x4*)((char*)sM + d * 256 + (((w * 16 + r0) * 2) ^ ((d & 7) << 4))) = q;
  }
  BARRIER();

  // ---- Ph8: commit c10->r1; acc = Adj@V1 (LAST read of counts); c11 stays in flight
  stW32(sW[1], t, st0);
#pragma unroll
  for (int n = 0; n < 8; n++) acc[n] = zero;
  for (int kb = 0; kb < 4; kb++) {
    bf16x8 aF = adjFrag(sC, invRow, w * 16, kb * 32, lane);
#pragma unroll
    for (int n = 0; n < 8; n++)
      acc[n] = MFMA16(aF, fragM(sM, n * 16, kb * 32, lane), acc[n]);
  }
  BARRIER();

  // ---- Ph9: commit c11->D (counts dead); issue c12,c13; acc += hA0@c8 + hA1@c9; mwr
  stW32(sD, t, st1);
  st0 = stG32(wbf + 49152, 128, 0, t);   // c12
  st1 = stG32(wbf + 49152, 128, 32, t);  // c13
  float mwr[4];
#pragma unroll
  for (int r = 0; r < 4; r++) mwr[r] = mwt[(size_t)gb * 128 + w * 16 + r0 + r];
#pragma unroll
  for (int n = 0; n < 8; n++) acc[n] = MFMA16(hA0, fragW32(sW[2], n * 16, lane), acc[n]);
#pragma unroll
  for (int n = 0; n < 8; n++) acc[n] = MFMA16(hA1, fragW32(sW[0], n * 16, lane), acc[n]);
  BARRIER();

  // ---- Ph10: commit c12->r2, c13->r0; issue c14,c15; acc += hA2@c10 + hA3@c11(D);
  //            BN1 epi -> h2 + pool  (no hA reload: Ph11/12 read h2 from sM)
  stW32(sW[2], t, st0);
  stW32(sW[0], t, st1);
  st0 = stG32(wbf + 49152, 128, 64, t);  // c14
  st1 = stG32(wbf + 49152, 128, 96, t);  // c15
#pragma unroll
  for (int n = 0; n < 8; n++) acc[n] = MFMA16(hA2, fragW32(sW[1], n * 16, lane), acc[n]);
#pragma unroll
  for (int n = 0; n < 8; n++) acc[n] = MFMA16(hA3, fragW32(sD, n * 16, lane), acc[n]);
#pragma unroll
  for (int n = 0; n < 8; n++) {
    int d = n * 16 + col;
    float mul = cst[256 + d], add = cst[384 + d];
    float csum = 0.f;
#pragma unroll
    for (int r = 0; r < 4; r++) {
      float v = acc[n][r] * mul + add;
      v = v > 0.f ? v : 0.01f * v;
      v *= mwr[r];
      putBf(sM, w * 16 + r0 + r, d, v);
      csum += v;
    }
    csum += __shfl_xor(csum, 16);
    csum += __shfl_xor(csum, 32);
    if (lane < 16) atomicAdd(&sPool[d], csum);
  }
  BARRIER();

  // ---- Ph11: commit c14->r1, c15->D; accP = h2@c12 + h2@c13 (h2 read from sM)
  stW32(sW[1], t, st0);
  stW32(sD, t, st1);
#pragma unroll
  for (int n = 0; n < 8; n++) acc[n] = zero;
  {
    bf16x8 h0 = fragM(sM, w * 16, 0, lane);
    bf16x8 h1 = fragM(sM, w * 16, 32, lane);
#pragma unroll
    for (int n = 0; n < 8; n++) acc[n] = MFMA16(h0, fragW32(sW[2], n * 16, lane), acc[n]);
#pragma unroll
    for (int n = 0; n < 8; n++) acc[n] = MFMA16(h1, fragW32(sW[0], n * 16, lane), acc[n]);
  }
  BARRIER();

  // ---- Ph12: accP += h2@c14 + h2@c15(D); +ba leaky -> p own rows (reads precede writes)
  {
    bf16x8 h2f = fragM(sM, w * 16, 64, lane);
    bf16x8 h3f = fragM(sM, w * 16, 96, lane);
#pragma unroll
    for (int n = 0; n < 8; n++) acc[n] = MFMA16(h2f, fragW32(sW[1], n * 16, lane), acc[n]);
#pragma unroll
    for (int n = 0; n < 8; n++) acc[n] = MFMA16(h3f, fragW32(sD, n * 16, lane), acc[n]);
  }
#pragma unroll
  for (int n = 0; n < 8; n++) {
    int d = n * 16 + col;
    float bav = ba[d];
#pragma unroll
    for (int r = 0; r < 4; r++) {
      float v = acc[n][r] + bav;
      v = v > 0.f ? v : 0.01f * v;
      putBf(sM, w * 16 + r0 + r, d, v);
    }
  }
  BARRIER();  // p complete for all rows

  // ---- Ph13: pair tiles -> sigmoid -> row/col sums (pair never stored)
  {
    f32x4 acc2[2] = {zero, zero};
    for (int kb = 0; kb < 128; kb += 32) {
#pragma unroll
      for (int i = 0; i < 2; i++) {
        int T = w * 2 + i;
        bf16x8 a = fragM(sM, (T >> 2) * 16, kb, lane);       // pA rows mb..mb+15
        bf16x8 b = fragM(sM, 64 + (T & 3) * 16, kb, lane);   // pB rows nb..nb+15
        acc2[i] = MFMA16(a, b, acc2[i]);
      }
    }
#pragma unroll
    for (int i = 0; i < 2; i++) {
      int T = w * 2 + i, mb = (T >> 2) * 16, nb = (T & 3) * 16;
      float s0 = 1.f / (1.f + __expf(-acc2[i][0]));
      float s1 = 1.f / (1.f + __expf(-acc2[i][1]));
      float s2 = 1.f / (1.f + __expf(-acc2[i][2]));
      float s3 = 1.f / (1.f + __expf(-acc2[i][3]));
      // colsum: reduce the 4 gq groups (16 rows) in-register first, then 16-lane atomics
      float sc = s0 + s1 + s2 + s3;
      sc += __shfl_xor(sc, 16);
      sc += __shfl_xor(sc, 32);
      if (lane < 16) atomicAdd(&sV1[64 + nb + col], sc);
      // rowsum: butterfly over the 16 col lanes
#pragma unroll
      for (int m = 1; m < 16; m <<= 1) {
        s0 += __shfl_xor(s0, m);
        s1 += __shfl_xor(s1, m);
        s2 += __shfl_xor(s2, m);
        s3 += __shfl_xor(s3, m);
      }
      if (col < 4) {
        float v = col == 0 ? s0 : (col == 1 ? s1 : (col == 2 ? s2 : s3));
        atomicAdd(&sV1[mb + r0 + col], v);
      }
    }
  }
  BARRIER();

  // ---- Ph14: delta pool: sPool[d] += sum_node u[node]*p[node][d]; zero sOut (D dead)
  if (t == 0) S3f[512] = 0.f;
  {
    int d = t & 127, q = t >> 7;
    float s = 0.f;
#pragma unroll
    for (int i = 0; i < 32; i++) {
      int node = q * 32 + i;
      float u = sV1[node];
      float pv = bf2f(*(const unsigned short*)((const char*)sM + node * 256 +
                                               ((2 * d) ^ ((node & 7) << 4))));
      s += u * pv;
    }
    atomicAdd(&sPool[d], s);
  }
  BARRIER();

  // ---- Ph15: mv0 with folded 1/128 scale: t1 = leaky(pool/128 @ Wr0 + br0)
  {
    int d = t >> 2, q = t & 3;
    const float* row = wr0t + d * 128 + q * 32;
    float s = 0.f;
#pragma unroll
    for (int j = 0; j < 32; j++) s += sPool[q * 32 + j] * row[j];
    s += __shfl_xor(s, 1);
    s += __shfl_xor(s, 2);
    if (q == 0) {
      s = s * (1.f / 128.f) + br0[d];
      S3f[256 + d] = s > 0.f ? s : 0.01f * s;
    }
  }
  BARRIER();

  // ---- Ph16: mv1 + Wout dot via in-wave butterfly + one atomic per wave
  {
    int d = t >> 2, q = t & 3;
    const float* row = wr1t + d * 128 + q * 32;
    float s = 0.f;
#pragma unroll
    for (int j = 0; j < 32; j++) s += S3f[256 + q * 32 + j] * row[j];
    s += __shfl_xor(s, 1);
    s += __shfl_xor(s, 2);
    float v2 = 0.f;
    if (q == 0) {
      s += br1[d];
      s = s > 0.f ? s : 0.01f * s;
      v2 = s * Wout[d];
    }
#pragma unroll
    for (int m = 1; m < 64; m <<= 1) v2 += __shfl_xor(v2, m);
    if (lane == 0) atomicAdd(&S3f[512], v2);
  }
  BARRIER();
  if (t == 0) out[gb] = S3f[512] + bout[0];
}

extern "C" void kernel_launch(void* const* d_in, const int* in_sizes, int n_in,
                              void* d_out, int out_size, void* d_ws, size_t ws_size,
                              hipStream_t stream) {
  const float* x     = (const float*)d_in[0];
  const float* mwt   = (const float*)d_in[1];
  const float* Wc0s  = (const float*)d_in[2];
  const float* Wc0n  = (const float*)d_in[3];
  const float* bc0   = (const float*)d_in[4];
  const float* g0    = (const float*)d_in[5];
  const float* b0    = (const float*)d_in[6];
  const float* m0    = (const float*)d_in[7];
  const float* v0    = (const float*)d_in[8];
  const float* Wc1s  = (const float*)d_in[9];
  const float* Wc1n  = (const float*)d_in[10];
  const float* bc1   = (const float*)d_in[11];
  const float* g1    = (const float*)d_in[12];
  const float* b1    = (const float*)d_in[13];
  const float* m1    = (const float*)d_in[14];
  const float* v1    = (const float*)d_in[15];
  const float* Wa    = (const float*)d_in[16];
  const float* ba    = (const float*)d_in[17];
  const float* Wr0   = (const float*)d_in[18];
  const float* br0   = (const float*)d_in[19];
  const float* Wr1   = (const float*)d_in[20];
  const float* br1   = (const float*)d_in[21];
  const float* Wout  = (const float*)d_in[22];
  const float* bout  = (const float*)d_in[23];
  const int*   ei    = (const int*)d_in[24];

  unsigned short* wbf = (unsigned short*)d_ws;                 // 131072 B
  float* cst    = (float*)((char*)d_ws + 131072);              // 2048 B
  float* wr0t   = (float*)((char*)d_ws + 133120);              // 65536 B
  float* wr1t   = (float*)((char*)d_ws + 198656);              // 65536 B

  prep_kernel<<<dim3(225), dim3(256), 0, stream>>>(Wc0s, Wc0n, Wc1s, Wc1n, Wa,
                                                   bc0, g0, b0, m0, v0,
                                                   bc1, g1, b1, m1, v1,
                                                   Wr0, Wr1, wbf, cst, wr0t, wr1t);
  gnn_fused<<<dim3(2048), dim3(512), 0, stream>>>(x, mwt, ei, wbf, cst, ba,
                                                  wr0t, br0, wr1t, br1, Wout, bout,
                                                  (float*)d_out);
}